// Round 13
// baseline (244.863 us; speedup 1.0000x reference)
//
#include <hip/hip_runtime.h>
#include <hip/hip_bf16.h>

// GNN attention layer. V=50000, E=800000, D=H=128. Inputs f32, OUTPUT f32.
//
// R24: R23 confirmed the XCD swizzle (FETCH 63->25.9 MB, ideal) but dur
// pinned ~45: gru is per-wave LATENCY-bound. Wave lifetime = 12 us (~29k cyc
// for ~2k cyc of work); 3 blocks/CU x 3.3 rounds = 44 us. Per tile ~5800 cyc:
// load->MFMA->LDS->barrier->epilogue fully serial, nothing overlaps across
// tiles. Fix: 2-deep REGISTER PIPELINE across the barrier - K-split left 56
// VGPR, so prefetch tile t+1's frags + xv BEFORE tile t's MFMA/barrier
// (R13's failed move, now affordable: +20 regs -> ~80, 3 blocks/CU kept at
// lb(256,3)). Single variable: gru loop only. Rest = R23 (XCD-grouped
// swizzle, int4-ILP LDS hist, chunk x range counting sort, atomic-free
// scatter, aggregate).

#define V_NODES 50000
#define E_EDGES 800000
#define D_FEAT  128
#define GCHUNK  5             // tiles per chunk (625 chunks x 8 cg = 5000 tasks)
#define WS_BLOCKS 1250        // np: 5000 waves / 4 per block
#define GRU_BLOCKS 2528       // gru: 8 xcds x 79 slot-groups x 4 pair-blocks

#define NCHUNK  49            // ceil(800000/16384) edge chunks
#define CHUNK_E 16384         // edges per chunk (e >> 14)
#define RANGES  4             // node ranges per chunk
#define NODE_R  12500         // nodes per range (25 KB packed LDS histogram)
#define HISTG   (NCHUNK * RANGES)   // 196 hist blocks
#define SCAN_BLOCKS 196       // ceil(50000/256)

typedef short bf16x8 __attribute__((ext_vector_type(8)));  // 8 bf16 in 4 VGPRs
typedef float f32x4  __attribute__((ext_vector_type(4)));
typedef unsigned short u16x4 __attribute__((ext_vector_type(4)));

// small-tensor bf16 pool element offsets
#define OFF_WEDGE 0
#define OFF_WPROJ 256
#define OFF_WIH   16640
#define OFF_WHH   65792
#define OFF_BEDGE 114944
#define OFF_BPROJ 114945
#define OFF_BIH   115073
#define OFF_BHH   115457
#define SMALL_TOTAL 115841
#define CONV_X_BLOCKS   6250   // 1.6M u16x4 / 256
#define CONV_S_BLOCKS   453
#define HIST_BLOCKS     3125   // 800000/256 (edge scatter grid)

// ---- device-global scratch (~58 MB; immune to ws_size) ----
__device__ int   g_is_bf16;
__device__ float g_pd[V_NODES];
__device__ float g_ps[V_NODES];
__device__ __attribute__((aligned(16))) unsigned int g_mat[NCHUNK * V_NODES]; // counts -> bases
__device__ int   g_row_off[V_NODES + 1];
__device__ int   g_blocksum[SCAN_BLOCKS];
__device__ int   g_blockoff[SCAN_BLOCKS];
__device__ unsigned short g_rank16[E_EDGES];    // within-chunk rank
__device__ __attribute__((aligned(16))) int2 g_s_pair[E_EDGES];  // {src, bits(w)}
__device__ __attribute__((aligned(16))) unsigned short g_xbf[V_NODES * D_FEAT];
__device__ __attribute__((aligned(16))) unsigned short g_wsmall[SMALL_TOTAL + 15];
__device__ __attribute__((aligned(16))) unsigned short g_hv[V_NODES * D_FEAT];
__device__ __attribute__((aligned(16))) unsigned short g_ctx[V_NODES * D_FEAT];

static __device__ __forceinline__ float b2f(unsigned short u) {
  union { unsigned int i; float f; } v; v.i = ((unsigned int)u) << 16; return v.f;
}
static __device__ __forceinline__ unsigned short f2b(float f) {
  unsigned int i = __float_as_uint(f);
  unsigned int r = (i + 0x7FFFu + ((i >> 16) & 1u)) >> 16;  // RNE (NaN stays NaN)
  return (unsigned short)r;
}
static __device__ __forceinline__ bf16x8 load_frag(const unsigned short* p) {
  return *reinterpret_cast<const bf16x8*>(p);  // 16B-aligned vector load
}
static __device__ __forceinline__ float fast_rcp(float x) {
  return __builtin_amdgcn_rcpf(x);             // v_rcp_f32, ~1 ulp
}
static __device__ __forceinline__ float fast_sigmoid(float x) {
  return fast_rcp(1.f + __expf(-x));           // x<<0: exp->inf, rcp->0. ok
}
static __device__ __forceinline__ float fast_tanh(float y) {
  // 1 - 2/(e^{2y}+1); y>>0: exp->inf, rcp->0 -> 1; y<<0: exp->0 -> -1; NaN->NaN
  return 1.f - 2.f * fast_rcp(__expf(2.f * y) + 1.f);
}

// ---------------- P: dtype probe on x ----------------------------------------
__global__ void probe_kernel(const unsigned int* __restrict__ x)
{
  __shared__ int cnt;
  if (threadIdx.x == 0) cnt = 0;
  __syncthreads();
  const unsigned int w  = x[threadIdx.x];
  const unsigned int lo = w & 0xFFFFu;
  const unsigned int ex = (lo >> 7) & 0xFFu;
  if (lo != 0u && ex >= 118u && ex <= 132u) atomicAdd(&cnt, 1);
  __syncthreads();
  if (threadIdx.x == 0) g_is_bf16 = (cnt >= 200) ? 1 : 0;
}

// ---------------- C: fused convert-x | convert-smalls ------------------------
__global__ void conv_fused_kernel(
    const void* __restrict__ x,
    const void* p0, const void* p1, const void* p2, const void* p3,
    const void* p4, const void* p5, const void* p6, const void* p7)
{
  const int b = blockIdx.x;
  if (b < CONV_X_BLOCKS) {
    const int t = b * 256 + threadIdx.x;
    if (g_is_bf16) {
      reinterpret_cast<u16x4*>(g_xbf)[t] = reinterpret_cast<const u16x4*>(x)[t];
    } else {
      const float4 v = reinterpret_cast<const float4*>(x)[t];
      u16x4 o; o.x = f2b(v.x); o.y = f2b(v.y); o.z = f2b(v.z); o.w = f2b(v.w);
      reinterpret_cast<u16x4*>(g_xbf)[t] = o;
    }
  } else {
    const int i = (b - CONV_X_BLOCKS) * 256 + threadIdx.x;
    if (i >= SMALL_TOTAL) return;
    const int offs[9] = {OFF_WEDGE, OFF_WPROJ, OFF_WIH, OFF_WHH,
                         OFF_BEDGE, OFF_BPROJ, OFF_BIH, OFF_BHH, SMALL_TOTAL};
    const void* ps[8] = {p0, p1, p2, p3, p4, p5, p6, p7};
    int r = 0;
#pragma unroll
    for (int k = 0; k < 8; k++) if (i >= offs[k]) r = k;
    const int j = i - offs[r];
    g_wsmall[i] = g_is_bf16
        ? reinterpret_cast<const unsigned short*>(ps[r])[j]
        : f2b(reinterpret_cast<const float*>(ps[r])[j]);
  }
}

// ---------------- K1: hist(c,r) int4-ILP LDS + node_pre ----------------------
__global__ __launch_bounds__(256, 2) void np_hist_kernel(const int* __restrict__ dst)
{
  __shared__ unsigned int hloc[NODE_R / 2];  // 25 KB; 2 node counters per word
  const int b = blockIdx.x;
  if (b < HISTG) {                           // ---- chunk x range histogram ----
    const int c  = b >> 2;                   // chunk [0,49)
    const int r0 = (b & 3) * NODE_R;         // range base node
    for (int i = threadIdx.x; i < NODE_R / 2; i += 256) hloc[i] = 0u;
    __syncthreads();
    const int ebase = c * CHUNK_E;
    const int ecnt  = min(CHUNK_E, E_EDGES - ebase);   // always multiple of 4
    const int4* dst4 = reinterpret_cast<const int4*>(dst + ebase);
    const int n4 = ecnt >> 2;
    for (int i = threadIdx.x; i < n4; i += 256) {
      const int4 d4 = dst4[i];               // 4 edges per thread per iter
      const int e0 = ebase + (i << 2);
      const unsigned int rx = (unsigned int)(d4.x - r0);
      const unsigned int ry = (unsigned int)(d4.y - r0);
      const unsigned int rz = (unsigned int)(d4.z - r0);
      const unsigned int rw = (unsigned int)(d4.w - r0);
      if (rx < (unsigned int)NODE_R) {       // 4 independent atomics pipeline
        const unsigned int sh = (rx & 1u) << 4;
        const unsigned int old = atomicAdd(&hloc[rx >> 1], 1u << sh);
        g_rank16[e0] = (unsigned short)((old >> sh) & 0xFFFFu);
      }
      if (ry < (unsigned int)NODE_R) {
        const unsigned int sh = (ry & 1u) << 4;
        const unsigned int old = atomicAdd(&hloc[ry >> 1], 1u << sh);
        g_rank16[e0 + 1] = (unsigned short)((old >> sh) & 0xFFFFu);
      }
      if (rz < (unsigned int)NODE_R) {
        const unsigned int sh = (rz & 1u) << 4;
        const unsigned int old = atomicAdd(&hloc[rz >> 1], 1u << sh);
        g_rank16[e0 + 2] = (unsigned short)((old >> sh) & 0xFFFFu);
      }
      if (rw < (unsigned int)NODE_R) {
        const unsigned int sh = (rw & 1u) << 4;
        const unsigned int old = atomicAdd(&hloc[rw >> 1], 1u << sh);
        g_rank16[e0 + 3] = (unsigned short)((old >> sh) & 0xFFFFu);
      }
    }
    __syncthreads();
    // vectorized writeout: one hloc word -> uint2 {lo count, hi count}
    uint2* mout = reinterpret_cast<uint2*>(&g_mat[c * V_NODES + r0]);
    for (int i = threadIdx.x; i < NODE_R / 2; i += 256) {
      const unsigned int w = hloc[i];
      mout[i] = make_uint2(w & 0xFFFFu, w >> 16);
    }
    return;
  }
  // ---- node_pre: wave-task g -> col-group cg, tile chunk ----
  const int g     = (b - HISTG) * 4 + (threadIdx.x >> 6);
  const int lane  = threadIdx.x & 63;
  const int cg    = g & 7;
  const int chunk = g >> 3;                  // [0, 625)
  const int col   = lane & 15;
  const int quad  = lane >> 4;
  const int h     = 16 * cg + col;

  // resident B fragments: W_proj rows [16cg, 16cg+16)
  bf16x8 bw[4];
#pragma unroll
  for (int kk = 0; kk < 4; kk++)
    bw[kk] = load_frag(g_wsmall + OFF_WPROJ + h * D_FEAT + kk * 32 + quad * 8);
  // cg 0 also owns the edge projections (cols 0/1 of W_edge)
  bf16x8 be[4];
#pragma unroll
  for (int kk = 0; kk < 4; kk++) { be[kk] = bf16x8{0,0,0,0,0,0,0,0}; }
  if (cg == 0 && col < 2) {
#pragma unroll
    for (int kk = 0; kk < 4; kk++)
      be[kk] = load_frag(g_wsmall + OFF_WEDGE + col * D_FEAT + kk * 32 + quad * 8);
  }
  const float bp = b2f(g_wsmall[OFF_BPROJ + h]);

  const int t0 = chunk * GCHUNK;
  bf16x8 a[4];
#pragma unroll
  for (int kk = 0; kk < 4; kk++)
    a[kk] = load_frag(g_xbf + (t0 * 16 + col) * D_FEAT + kk * 32 + quad * 8);
  for (int t = t0; t < t0 + GCHUNK; t++) {
    // prefetch next tile's A while current tile computes (uniform clamp)
    const int tn = (t + 1 < t0 + GCHUNK) ? t + 1 : t;
    bf16x8 na[4];
#pragma unroll
    for (int kk = 0; kk < 4; kk++)
      na[kk] = load_frag(g_xbf + (tn * 16 + col) * D_FEAT + kk * 32 + quad * 8);
    f32x4 acc; acc[0]=0.f; acc[1]=0.f; acc[2]=0.f; acc[3]=0.f;
#pragma unroll
    for (int kk = 0; kk < 4; kk++)
      acc = __builtin_amdgcn_mfma_f32_16x16x32_bf16(a[kk], bw[kk], acc, 0, 0, 0);
#pragma unroll
    for (int r = 0; r < 4; r++)
      g_hv[(t * 16 + quad * 4 + r) * D_FEAT + h] = f2b(acc[r] + bp);
    if (cg == 0) {
      f32x4 acce; acce[0]=0.f; acce[1]=0.f; acce[2]=0.f; acce[3]=0.f;
#pragma unroll
      for (int kk = 0; kk < 4; kk++)
        acce = __builtin_amdgcn_mfma_f32_16x16x32_bf16(a[kk], be[kk], acce, 0, 0, 0);
      if (col == 0) {
#pragma unroll
        for (int r = 0; r < 4; r++) g_pd[t * 16 + quad * 4 + r] = acce[r];
      } else if (col == 1) {
#pragma unroll
        for (int r = 0; r < 4; r++) g_ps[t * 16 + quad * 4 + r] = acce[r];
      }
    }
#pragma unroll
    for (int kk = 0; kk < 4; kk++) a[kk] = na[kk];
  }
}

// ---------------- K3a: column-sum over chunks + block-local scan --------------
__global__ __launch_bounds__(256) void scan_a_kernel()
{
  __shared__ int lds[256];
  const int b = blockIdx.x, t = threadIdx.x;
  const int idx = b * 256 + t;
  int v = 0;
  if (idx < V_NODES) {
#pragma unroll 7
    for (int c = 0; c < NCHUNK; c++) v += (int)g_mat[c * V_NODES + idx];
  }
  lds[t] = v;
  __syncthreads();
  for (int off = 1; off < 256; off <<= 1) {
    int tmp = (t >= off) ? lds[t - off] : 0;
    __syncthreads();
    lds[t] += tmp;
    __syncthreads();
  }
  if (idx < V_NODES) g_row_off[idx] = lds[t] - v;   // local exclusive prefix
  if (t == 255) g_blocksum[b] = lds[255];
}

// ---------------- K3b: scan the 196 block totals (1 small block) --------------
__global__ __launch_bounds__(256) void scan_b_kernel()
{
  __shared__ int lds[256];
  const int t = threadIdx.x;
  const int v = (t < SCAN_BLOCKS) ? g_blocksum[t] : 0;
  lds[t] = v;
  __syncthreads();
  for (int off = 1; off < 256; off <<= 1) {
    int tmp = (t >= off) ? lds[t - off] : 0;
    __syncthreads();
    lds[t] += tmp;
    __syncthreads();
  }
  if (t < SCAN_BLOCKS) g_blockoff[t] = lds[t] - v;
  if (t == 255) g_row_off[V_NODES] = lds[255];      // total = E
}

// ---------------- K3c: add block offsets -------------------------------------
__global__ __launch_bounds__(256) void scan_c_kernel()
{
  const int b = blockIdx.x, t = threadIdx.x;
  const int idx = b * 256 + t;
  if (idx >= V_NODES) return;
  g_row_off[idx] += g_blockoff[b];
}

// ---------------- K3d: matrix counts -> segment bases (in-place) -------------
__global__ __launch_bounds__(256) void scan_m2_kernel()
{
  const int idx = blockIdx.x * 256 + threadIdx.x;
  if (idx >= V_NODES) return;
  int running = g_row_off[idx];
#pragma unroll 7
  for (int c = 0; c < NCHUNK; c++) {
    const unsigned int cnt = g_mat[c * V_NODES + idx];
    g_mat[c * V_NODES + idx] = (unsigned int)running;
    running += (int)cnt;
  }
}

// ---------------- K4: edge scatter — atomic-free, one 8B write/edge ----------
__global__ void edge_scatter_kernel(
    const int* __restrict__ src, const int* __restrict__ dst, int E)
{
  int e = blockIdx.x * blockDim.x + threadIdx.x;
  if (e >= E) return;
  const int d = dst[e], sn = src[e];
  float logit = g_pd[d] + g_ps[sn] + b2f(g_wsmall[OFF_BEDGE]);
  logit = (logit >= 0.f) ? logit : 0.01f * logit;           // LeakyReLU(0.01)
  const float w = __expf(logit);                            // no max-sub: cancels
  const int c = e >> 14;                                    // chunk
  const int pos = (int)g_mat[c * V_NODES + d] + (int)g_rank16[e];
  g_s_pair[pos] = make_int2(sn, __float_as_int(w));
}

// ---------------- K5: aggregation, 4 nodes/block (one per wave) --------------
__global__ __launch_bounds__(256) void aggregate_kernel()
{
  const int v = blockIdx.x * 4 + (threadIdx.x >> 6);   // grid 12500 -> v < 50000
  const int lane = threadIdx.x & 63;                   // lane: cols 2l, 2l+1
  const int beg = g_row_off[v], end = g_row_off[v + 1];
  float accx = 0.f, accy = 0.f, ssum = 0.f;
  int i = beg;
  for (; i + 4 <= end; i += 4) {       // 4 gathers in flight
    const int2 q0 = g_s_pair[i],     q1 = g_s_pair[i + 1],
               q2 = g_s_pair[i + 2], q3 = g_s_pair[i + 3];
    const float w0 = __int_as_float(q0.y), w1 = __int_as_float(q1.y),
                w2 = __int_as_float(q2.y), w3 = __int_as_float(q3.y);
    const unsigned int p0 = *reinterpret_cast<const unsigned int*>(g_hv + q0.x * D_FEAT + lane * 2);
    const unsigned int p1 = *reinterpret_cast<const unsigned int*>(g_hv + q1.x * D_FEAT + lane * 2);
    const unsigned int p2 = *reinterpret_cast<const unsigned int*>(g_hv + q2.x * D_FEAT + lane * 2);
    const unsigned int p3 = *reinterpret_cast<const unsigned int*>(g_hv + q3.x * D_FEAT + lane * 2);
    ssum += (w0 + w1) + (w2 + w3);
    accx += w0 * b2f((unsigned short)(p0 & 0xFFFFu)) + w1 * b2f((unsigned short)(p1 & 0xFFFFu))
          + w2 * b2f((unsigned short)(p2 & 0xFFFFu)) + w3 * b2f((unsigned short)(p3 & 0xFFFFu));
    accy += w0 * b2f((unsigned short)(p0 >> 16)) + w1 * b2f((unsigned short)(p1 >> 16))
          + w2 * b2f((unsigned short)(p2 >> 16)) + w3 * b2f((unsigned short)(p3 >> 16));
  }
  for (; i < end; i++) {
    const int2 q = g_s_pair[i];
    const float w = __int_as_float(q.y);
    ssum += w;
    const unsigned int pair =
        *reinterpret_cast<const unsigned int*>(g_hv + q.x * D_FEAT + lane * 2);
    accx += w * b2f((unsigned short)(pair & 0xFFFFu));
    accy += w * b2f((unsigned short)(pair >> 16));
  }
  const float inv = (end > beg) ? (1.0f / ssum) : 0.0f;     // empty segment -> c=0
  float c0 = accx * inv, c1 = accy * inv;
  c0 = (c0 > 0.f) ? c0 : (__expf(c0) - 1.f);                // elu
  c1 = (c1 > 0.f) ? c1 : (__expf(c1) - 1.f);
  const unsigned int outp = ((unsigned int)f2b(c1) << 16) | (unsigned int)f2b(c0);
  *reinterpret_cast<unsigned int*>(g_ctx + v * D_FEAT + lane * 2) = outp;
}

// ---------------- K6: GRU K-split + XCD swizzle + 2-deep register pipeline ----
__global__ __launch_bounds__(256, 3) void gru_kernel(const float* __restrict__ xf32,
                                                     float* __restrict__ out)
{
  // XCD-grouping swizzle (R23-verified: FETCH 63->25.9 MB).
  const int d = blockIdx.x;
  const int x = d & 7;                       // XCD (round-robin dispatch)
  const int s = d >> 3;                      // slot on that XCD [0, 316)
  const int chunk = x + 8 * (s >> 2);        // 4 slots -> same chunk
  if (chunk >= 625) return;                  // block-uniform guard (28 blocks)
  __shared__ float part[2][2][16][64];       // [buf][cgs][acc_idx][lane] 16 KB
  const int pairb = (s & 3) << 1;            // cg pair base: 0,2,4,6
  const int wid   = threadIdx.x >> 6;        // 0..3
  const int lane  = threadIdx.x & 63;
  const int ks    = wid >> 1;                // K-half: 0 -> kk 0,1 ; 1 -> kk 2,3
  const int cgs   = wid & 1;                 // task slot within pair
  const int cg    = pairb + cgs;             // 0..7
  const int col   = lane & 15;
  const int quad  = lane >> 4;
  const int h     = 16 * cg + col;
  const unsigned short* W_ih = g_wsmall + OFF_WIH;
  const unsigned short* W_hh = g_wsmall + OFF_WHH;
  const int isb = g_is_bf16;

  // biases only on the combining (ks=0) wave
  float br = 0.f, bz = 0.f, bn = 0.f, bh_ = 0.f;
  if (ks == 0) {
    br  = b2f(g_wsmall[OFF_BIH + h])       + b2f(g_wsmall[OFF_BHH + h]);
    bz  = b2f(g_wsmall[OFF_BIH + 128 + h]) + b2f(g_wsmall[OFF_BHH + 128 + h]);
    bn  = b2f(g_wsmall[OFF_BIH + 256 + h]);
    bh_ = b2f(g_wsmall[OFF_BHH + 256 + h]);
  }

  // resident B fragments: K-half only -> 12 frags = 48 regs
  bf16x8 bIHr[2], bHHr[2], bIHz[2], bHHz[2], bIHn[2], bHHn[2];
#pragma unroll
  for (int j = 0; j < 2; j++) {
    const int ko = (2 * ks + j) * 32 + quad * 8;
    bIHr[j] = load_frag(W_ih + h * D_FEAT + ko);
    bHHr[j] = load_frag(W_hh + h * D_FEAT + ko);
    bIHz[j] = load_frag(W_ih + (128 + h) * D_FEAT + ko);
    bHHz[j] = load_frag(W_hh + (128 + h) * D_FEAT + ko);
    bIHn[j] = load_frag(W_ih + (256 + h) * D_FEAT + ko);
    bHHn[j] = load_frag(W_hh + (256 + h) * D_FEAT + ko);
  }

  const int t0 = chunk * GCHUNK;
  // ---- pipeline prologue: load tile t0's operands ----
  bf16x8 ax[2], ac[2];
  float xv[4];
#pragma unroll
  for (int j = 0; j < 2; j++) {
    const int o = (t0 * 16 + col) * D_FEAT + (2 * ks + j) * 32 + quad * 8;
    ax[j] = load_frag(g_xbf + o);
    ac[j] = load_frag(g_ctx + o);
  }
  if (ks == 0) {
    if (isb) {
#pragma unroll
      for (int r = 0; r < 4; r++)
        xv[r] = b2f(g_xbf[(t0 * 16 + quad * 4 + r) * D_FEAT + h]);
    } else {
#pragma unroll
      for (int r = 0; r < 4; r++)
        xv[r] = xf32[(t0 * 16 + quad * 4 + r) * D_FEAT + h];
    }
  }
  for (int t = t0; t < t0 + GCHUNK; t++) {
    // ---- prefetch tile t+1 BEFORE t's MFMA/barrier/epilogue (clamped) ----
    const int tn = (t + 1 < t0 + GCHUNK) ? t + 1 : t;
    bf16x8 nax[2], nac[2];
    float nxv[4];
#pragma unroll
    for (int j = 0; j < 2; j++) {
      const int o = (tn * 16 + col) * D_FEAT + (2 * ks + j) * 32 + quad * 8;
      nax[j] = load_frag(g_xbf + o);
      nac[j] = load_frag(g_ctx + o);
    }
    if (ks == 0) {
      if (isb) {
#pragma unroll
        for (int r = 0; r < 4; r++)
          nxv[r] = b2f(g_xbf[(tn * 16 + quad * 4 + r) * D_FEAT + h]);
      } else {
#pragma unroll
        for (int r = 0; r < 4; r++)
          nxv[r] = xf32[(tn * 16 + quad * 4 + r) * D_FEAT + h];
      }
    }
    f32x4 racc, zacc, niacc, nhacc;
    racc[0]=br;  racc[1]=br;  racc[2]=br;  racc[3]=br;     // ks=1: zeros
    zacc[0]=bz;  zacc[1]=bz;  zacc[2]=bz;  zacc[3]=bz;
    niacc[0]=bn; niacc[1]=bn; niacc[2]=bn; niacc[3]=bn;
    nhacc[0]=bh_; nhacc[1]=bh_; nhacc[2]=bh_; nhacc[3]=bh_;
#pragma unroll
    for (int j = 0; j < 2; j++) {
      racc  = __builtin_amdgcn_mfma_f32_16x16x32_bf16(ac[j], bIHr[j], racc, 0, 0, 0);
      racc  = __builtin_amdgcn_mfma_f32_16x16x32_bf16(ax[j], bHHr[j], racc, 0, 0, 0);
      zacc  = __builtin_amdgcn_mfma_f32_16x16x32_bf16(ac[j], bIHz[j], zacc, 0, 0, 0);
      zacc  = __builtin_amdgcn_mfma_f32_16x16x32_bf16(ax[j], bHHz[j], zacc, 0, 0, 0);
      niacc = __builtin_amdgcn_mfma_f32_16x16x32_bf16(ac[j], bIHn[j], niacc, 0, 0, 0);
      nhacc = __builtin_amdgcn_mfma_f32_16x16x32_bf16(ax[j], bHHn[j], nhacc, 0, 0, 0);
    }
    const int buf = t & 1;                   // block-uniform (shared chunk)
    if (ks == 1) {                           // producer: partials -> LDS
#pragma unroll
      for (int r = 0; r < 4; r++) {
        part[buf][cgs][r][lane]      = racc[r];
        part[buf][cgs][4 + r][lane]  = zacc[r];
        part[buf][cgs][8 + r][lane]  = niacc[r];
        part[buf][cgs][12 + r][lane] = nhacc[r];
      }
    }
    __syncthreads();                         // one barrier per tile (dbuf'd)
    if (ks == 0) {                           // combiner: add + epilogue
#pragma unroll
      for (int r = 0; r < 4; r++) {
        racc[r]  += part[buf][cgs][r][lane];
        zacc[r]  += part[buf][cgs][4 + r][lane];
        niacc[r] += part[buf][cgs][8 + r][lane];
        nhacc[r] += part[buf][cgs][12 + r][lane];
      }
#pragma unroll
      for (int r = 0; r < 4; r++) {
        const int vrow = t * 16 + quad * 4 + r;
        const float rg = fast_sigmoid(racc[r]);
        const float zg = fast_sigmoid(zacc[r]);
        const float n  = fast_tanh(niacc[r] + rg * nhacc[r]);
        const float hn = (1.f - zg) * n + zg * xv[r];
        out[vrow * D_FEAT + h] = (hn < 0.f) ? 0.f : hn;  // relu; NaN passes
      }
    }
    // ---- rotate pipeline registers ----
#pragma unroll
    for (int j = 0; j < 2; j++) { ax[j] = nax[j]; ac[j] = nac[j]; }
    if (ks == 0) {
#pragma unroll
      for (int r = 0; r < 4; r++) xv[r] = nxv[r];
    }
  }
}

// ---------------- launch ------------------------------------------------------
extern "C" void kernel_launch(void* const* d_in, const int* in_sizes, int n_in,
                              void* d_out, int out_size, void* d_ws, size_t ws_size,
                              hipStream_t stream)
{
  (void)d_ws; (void)ws_size; (void)out_size;

  // resolve inputs by element count (same-size pairs keep dict order)
  int ix = -1, iWe = -1, ibe = -1, iWp = -1, ibp = -1,
      iWih = -1, iWhh = -1, ibih = -1, ibhh = -1, isrc = -1, idst = -1;
  for (int i = 0; i < n_in; i++) {
    const int s = in_sizes[i];
    if      (s == 6400000) ix = i;
    else if (s == 256)     iWe = i;
    else if (s == 1)       ibe = i;
    else if (s == 16384)   iWp = i;
    else if (s == 128)     ibp = i;
    else if (s == 49152)   { if (iWih < 0) iWih = i; else iWhh = i; }
    else if (s == 384)     { if (ibih < 0) ibih = i; else ibhh = i; }
    else if (s == 800000)  { if (isrc < 0) isrc = i; else idst = i; }
  }
  if (ix < 0 || iWe < 0 || ibe < 0 || iWp < 0 || ibp < 0 || iWih < 0 ||
      iWhh < 0 || ibih < 0 || ibhh < 0 || isrc < 0 || idst < 0) {
    ix = 0; iWe = 1; ibe = 2; iWp = 3; ibp = 4;           // dict-order fallback
    iWih = 5; iWhh = 6; ibih = 7; ibhh = 8; isrc = 9; idst = 10;
  }

  const int* src = (const int*)d_in[isrc];
  const int* dst = (const int*)d_in[idst];
  float* out = (float*)d_out;

  probe_kernel<<<1, 256, 0, stream>>>((const unsigned int*)d_in[ix]);
  conv_fused_kernel<<<CONV_X_BLOCKS + CONV_S_BLOCKS, 256, 0, stream>>>(
      d_in[ix],
      d_in[iWe], d_in[iWp], d_in[iWih], d_in[iWhh],
      d_in[ibe], d_in[ibp], d_in[ibih], d_in[ibhh]);
  np_hist_kernel<<<HISTG + WS_BLOCKS, 256, 0, stream>>>(dst);
  scan_a_kernel<<<SCAN_BLOCKS, 256, 0, stream>>>();
  scan_b_kernel<<<1, 256, 0, stream>>>();
  scan_c_kernel<<<SCAN_BLOCKS, 256, 0, stream>>>();
  scan_m2_kernel<<<SCAN_BLOCKS, 256, 0, stream>>>();
  edge_scatter_kernel<<<HIST_BLOCKS, 256, 0, stream>>>(src, dst, E_EDGES);
  aggregate_kernel<<<V_NODES / 4, 256, 0, stream>>>();
  gru_kernel<<<GRU_BLOCKS, 256, 0, stream>>>((const float*)d_in[ix], out);
}

// Round 14
// 233.905 us; speedup vs baseline: 1.0468x; 1.0468x over previous
//
#include <hip/hip_runtime.h>
#include <hip/hip_bf16.h>

// GNN attention layer. V=50000, E=800000, D=H=128. Inputs f32, OUTPUT f32.
//
// R25: gru is latency-floored at ~44 us across 5 decompositions (R19/20/23/24:
// 44-50 us at 26-63 MB FETCH, Occ 25-33%) - registers spent on pipelining are
// paid back in occupancy. Consolidate: (1) revert gru to R19 weight-stationary
// (44.4 us best) + R23-verified XCD-grouping swizzle (2 blocks/chunk share one
// L2: FETCH 38.4 -> ~29 MB expected); (2) fuse scan_b+c+m2 into one kernel
// (each of 196 blocks redundantly scans the 196 blocksums in LDS, adds its
// offset, walks the m2 base conversion) - launches 9 -> 7, ~10 us/launch
// serialization observed (sum of kernels ~140 us vs total ~240).
// Rest = R19 (int4-ILP LDS hist, chunk x range counting sort, atomic-free
// scatter, aggregate).

#define V_NODES 50000
#define E_EDGES 800000
#define D_FEAT  128
#define GCHUNK  5             // tiles per chunk (625 chunks x 8 cg = 5000 tasks)
#define WS_BLOCKS 1250        // np: 5000 waves / 4 per block
#define GRU_BLOCKS 1264       // gru: 8 xcds x 158 slots (2 blocks/chunk, guard)

#define NCHUNK  49            // ceil(800000/16384) edge chunks
#define CHUNK_E 16384         // edges per chunk (e >> 14)
#define RANGES  4             // node ranges per chunk
#define NODE_R  12500         // nodes per range (25 KB packed LDS histogram)
#define HISTG   (NCHUNK * RANGES)   // 196 hist blocks
#define SCAN_BLOCKS 196       // ceil(50000/256)

typedef short bf16x8 __attribute__((ext_vector_type(8)));  // 8 bf16 in 4 VGPRs
typedef float f32x4  __attribute__((ext_vector_type(4)));
typedef unsigned short u16x4 __attribute__((ext_vector_type(4)));

// small-tensor bf16 pool element offsets
#define OFF_WEDGE 0
#define OFF_WPROJ 256
#define OFF_WIH   16640
#define OFF_WHH   65792
#define OFF_BEDGE 114944
#define OFF_BPROJ 114945
#define OFF_BIH   115073
#define OFF_BHH   115457
#define SMALL_TOTAL 115841
#define CONV_X_BLOCKS   6250   // 1.6M u16x4 / 256
#define CONV_S_BLOCKS   453
#define HIST_BLOCKS     3125   // 800000/256 (edge scatter grid)

// ---- device-global scratch (~58 MB; immune to ws_size) ----
__device__ int   g_is_bf16;
__device__ float g_pd[V_NODES];
__device__ float g_ps[V_NODES];
__device__ __attribute__((aligned(16))) unsigned int g_mat[NCHUNK * V_NODES]; // counts -> bases
__device__ int   g_row_off[V_NODES + 1];
__device__ int   g_blocksum[SCAN_BLOCKS];
__device__ unsigned short g_rank16[E_EDGES];    // within-chunk rank
__device__ __attribute__((aligned(16))) int2 g_s_pair[E_EDGES];  // {src, bits(w)}
__device__ __attribute__((aligned(16))) unsigned short g_xbf[V_NODES * D_FEAT];
__device__ __attribute__((aligned(16))) unsigned short g_wsmall[SMALL_TOTAL + 15];
__device__ __attribute__((aligned(16))) unsigned short g_hv[V_NODES * D_FEAT];
__device__ __attribute__((aligned(16))) unsigned short g_ctx[V_NODES * D_FEAT];

static __device__ __forceinline__ float b2f(unsigned short u) {
  union { unsigned int i; float f; } v; v.i = ((unsigned int)u) << 16; return v.f;
}
static __device__ __forceinline__ unsigned short f2b(float f) {
  unsigned int i = __float_as_uint(f);
  unsigned int r = (i + 0x7FFFu + ((i >> 16) & 1u)) >> 16;  // RNE (NaN stays NaN)
  return (unsigned short)r;
}
static __device__ __forceinline__ bf16x8 load_frag(const unsigned short* p) {
  return *reinterpret_cast<const bf16x8*>(p);  // 16B-aligned vector load
}
static __device__ __forceinline__ float fast_rcp(float x) {
  return __builtin_amdgcn_rcpf(x);             // v_rcp_f32, ~1 ulp
}
static __device__ __forceinline__ float fast_sigmoid(float x) {
  return fast_rcp(1.f + __expf(-x));           // x<<0: exp->inf, rcp->0. ok
}
static __device__ __forceinline__ float fast_tanh(float y) {
  // 1 - 2/(e^{2y}+1); y>>0: exp->inf, rcp->0 -> 1; y<<0: exp->0 -> -1; NaN->NaN
  return 1.f - 2.f * fast_rcp(__expf(2.f * y) + 1.f);
}

// ---------------- P: dtype probe on x ----------------------------------------
__global__ void probe_kernel(const unsigned int* __restrict__ x)
{
  __shared__ int cnt;
  if (threadIdx.x == 0) cnt = 0;
  __syncthreads();
  const unsigned int w  = x[threadIdx.x];
  const unsigned int lo = w & 0xFFFFu;
  const unsigned int ex = (lo >> 7) & 0xFFu;
  if (lo != 0u && ex >= 118u && ex <= 132u) atomicAdd(&cnt, 1);
  __syncthreads();
  if (threadIdx.x == 0) g_is_bf16 = (cnt >= 200) ? 1 : 0;
}

// ---------------- C: fused convert-x | convert-smalls ------------------------
__global__ void conv_fused_kernel(
    const void* __restrict__ x,
    const void* p0, const void* p1, const void* p2, const void* p3,
    const void* p4, const void* p5, const void* p6, const void* p7)
{
  const int b = blockIdx.x;
  if (b < CONV_X_BLOCKS) {
    const int t = b * 256 + threadIdx.x;
    if (g_is_bf16) {
      reinterpret_cast<u16x4*>(g_xbf)[t] = reinterpret_cast<const u16x4*>(x)[t];
    } else {
      const float4 v = reinterpret_cast<const float4*>(x)[t];
      u16x4 o; o.x = f2b(v.x); o.y = f2b(v.y); o.z = f2b(v.z); o.w = f2b(v.w);
      reinterpret_cast<u16x4*>(g_xbf)[t] = o;
    }
  } else {
    const int i = (b - CONV_X_BLOCKS) * 256 + threadIdx.x;
    if (i >= SMALL_TOTAL) return;
    const int offs[9] = {OFF_WEDGE, OFF_WPROJ, OFF_WIH, OFF_WHH,
                         OFF_BEDGE, OFF_BPROJ, OFF_BIH, OFF_BHH, SMALL_TOTAL};
    const void* ps[8] = {p0, p1, p2, p3, p4, p5, p6, p7};
    int r = 0;
#pragma unroll
    for (int k = 0; k < 8; k++) if (i >= offs[k]) r = k;
    const int j = i - offs[r];
    g_wsmall[i] = g_is_bf16
        ? reinterpret_cast<const unsigned short*>(ps[r])[j]
        : f2b(reinterpret_cast<const float*>(ps[r])[j]);
  }
}

// ---------------- K1: hist(c,r) int4-ILP LDS + node_pre ----------------------
__global__ __launch_bounds__(256, 2) void np_hist_kernel(const int* __restrict__ dst)
{
  __shared__ unsigned int hloc[NODE_R / 2];  // 25 KB; 2 node counters per word
  const int b = blockIdx.x;
  if (b < HISTG) {                           // ---- chunk x range histogram ----
    const int c  = b >> 2;                   // chunk [0,49)
    const int r0 = (b & 3) * NODE_R;         // range base node
    for (int i = threadIdx.x; i < NODE_R / 2; i += 256) hloc[i] = 0u;
    __syncthreads();
    const int ebase = c * CHUNK_E;
    const int ecnt  = min(CHUNK_E, E_EDGES - ebase);   // always multiple of 4
    const int4* dst4 = reinterpret_cast<const int4*>(dst + ebase);
    const int n4 = ecnt >> 2;
    for (int i = threadIdx.x; i < n4; i += 256) {
      const int4 d4 = dst4[i];               // 4 edges per thread per iter
      const int e0 = ebase + (i << 2);
      const unsigned int rx = (unsigned int)(d4.x - r0);
      const unsigned int ry = (unsigned int)(d4.y - r0);
      const unsigned int rz = (unsigned int)(d4.z - r0);
      const unsigned int rw = (unsigned int)(d4.w - r0);
      if (rx < (unsigned int)NODE_R) {       // 4 independent atomics pipeline
        const unsigned int sh = (rx & 1u) << 4;
        const unsigned int old = atomicAdd(&hloc[rx >> 1], 1u << sh);
        g_rank16[e0] = (unsigned short)((old >> sh) & 0xFFFFu);
      }
      if (ry < (unsigned int)NODE_R) {
        const unsigned int sh = (ry & 1u) << 4;
        const unsigned int old = atomicAdd(&hloc[ry >> 1], 1u << sh);
        g_rank16[e0 + 1] = (unsigned short)((old >> sh) & 0xFFFFu);
      }
      if (rz < (unsigned int)NODE_R) {
        const unsigned int sh = (rz & 1u) << 4;
        const unsigned int old = atomicAdd(&hloc[rz >> 1], 1u << sh);
        g_rank16[e0 + 2] = (unsigned short)((old >> sh) & 0xFFFFu);
      }
      if (rw < (unsigned int)NODE_R) {
        const unsigned int sh = (rw & 1u) << 4;
        const unsigned int old = atomicAdd(&hloc[rw >> 1], 1u << sh);
        g_rank16[e0 + 3] = (unsigned short)((old >> sh) & 0xFFFFu);
      }
    }
    __syncthreads();
    // vectorized writeout: one hloc word -> uint2 {lo count, hi count}
    uint2* mout = reinterpret_cast<uint2*>(&g_mat[c * V_NODES + r0]);
    for (int i = threadIdx.x; i < NODE_R / 2; i += 256) {
      const unsigned int w = hloc[i];
      mout[i] = make_uint2(w & 0xFFFFu, w >> 16);
    }
    return;
  }
  // ---- node_pre: wave-task g -> col-group cg, tile chunk ----
  const int g     = (b - HISTG) * 4 + (threadIdx.x >> 6);
  const int lane  = threadIdx.x & 63;
  const int cg    = g & 7;
  const int chunk = g >> 3;                  // [0, 625)
  const int col   = lane & 15;
  const int quad  = lane >> 4;
  const int h     = 16 * cg + col;

  // resident B fragments: W_proj rows [16cg, 16cg+16)
  bf16x8 bw[4];
#pragma unroll
  for (int kk = 0; kk < 4; kk++)
    bw[kk] = load_frag(g_wsmall + OFF_WPROJ + h * D_FEAT + kk * 32 + quad * 8);
  // cg 0 also owns the edge projections (cols 0/1 of W_edge)
  bf16x8 be[4];
#pragma unroll
  for (int kk = 0; kk < 4; kk++) { be[kk] = bf16x8{0,0,0,0,0,0,0,0}; }
  if (cg == 0 && col < 2) {
#pragma unroll
    for (int kk = 0; kk < 4; kk++)
      be[kk] = load_frag(g_wsmall + OFF_WEDGE + col * D_FEAT + kk * 32 + quad * 8);
  }
  const float bp = b2f(g_wsmall[OFF_BPROJ + h]);

  const int t0 = chunk * GCHUNK;
  bf16x8 a[4];
#pragma unroll
  for (int kk = 0; kk < 4; kk++)
    a[kk] = load_frag(g_xbf + (t0 * 16 + col) * D_FEAT + kk * 32 + quad * 8);
  for (int t = t0; t < t0 + GCHUNK; t++) {
    // prefetch next tile's A while current tile computes (uniform clamp)
    const int tn = (t + 1 < t0 + GCHUNK) ? t + 1 : t;
    bf16x8 na[4];
#pragma unroll
    for (int kk = 0; kk < 4; kk++)
      na[kk] = load_frag(g_xbf + (tn * 16 + col) * D_FEAT + kk * 32 + quad * 8);
    f32x4 acc; acc[0]=0.f; acc[1]=0.f; acc[2]=0.f; acc[3]=0.f;
#pragma unroll
    for (int kk = 0; kk < 4; kk++)
      acc = __builtin_amdgcn_mfma_f32_16x16x32_bf16(a[kk], bw[kk], acc, 0, 0, 0);
#pragma unroll
    for (int r = 0; r < 4; r++)
      g_hv[(t * 16 + quad * 4 + r) * D_FEAT + h] = f2b(acc[r] + bp);
    if (cg == 0) {
      f32x4 acce; acce[0]=0.f; acce[1]=0.f; acce[2]=0.f; acce[3]=0.f;
#pragma unroll
      for (int kk = 0; kk < 4; kk++)
        acce = __builtin_amdgcn_mfma_f32_16x16x32_bf16(a[kk], be[kk], acce, 0, 0, 0);
      if (col == 0) {
#pragma unroll
        for (int r = 0; r < 4; r++) g_pd[t * 16 + quad * 4 + r] = acce[r];
      } else if (col == 1) {
#pragma unroll
        for (int r = 0; r < 4; r++) g_ps[t * 16 + quad * 4 + r] = acce[r];
      }
    }
#pragma unroll
    for (int kk = 0; kk < 4; kk++) a[kk] = na[kk];
  }
}

// ---------------- K3a: column-sum over chunks + block-local scan --------------
__global__ __launch_bounds__(256) void scan_a_kernel()
{
  __shared__ int lds[256];
  const int b = blockIdx.x, t = threadIdx.x;
  const int idx = b * 256 + t;
  int v = 0;
  if (idx < V_NODES) {
#pragma unroll 7
    for (int c = 0; c < NCHUNK; c++) v += (int)g_mat[c * V_NODES + idx];
  }
  lds[t] = v;
  __syncthreads();
  for (int off = 1; off < 256; off <<= 1) {
    int tmp = (t >= off) ? lds[t - off] : 0;
    __syncthreads();
    lds[t] += tmp;
    __syncthreads();
  }
  if (idx < V_NODES) g_row_off[idx] = lds[t] - v;   // local exclusive prefix
  if (t == 255) g_blocksum[b] = lds[255];
}

// ---------------- K3b: fused blocksum-scan + offset-add + m2 base walk --------
__global__ __launch_bounds__(256) void scan_bcm_kernel()
{
  __shared__ int lds[256];
  const int b = blockIdx.x, t = threadIdx.x;       // 196 blocks
  // every block redundantly scans the 196 block sums (trivial)
  const int v = (t < SCAN_BLOCKS) ? g_blocksum[t] : 0;
  lds[t] = v;
  __syncthreads();
  for (int off = 1; off < 256; off <<= 1) {
    int tmp = (t >= off) ? lds[t - off] : 0;
    __syncthreads();
    lds[t] += tmp;
    __syncthreads();
  }
  const int total = lds[255];                      // = E
  const int boff  = (b == 0) ? 0 : lds[b - 1];     // exclusive offset of block b
  const int idx = b * 256 + t;
  if (idx < V_NODES) {
    int running = g_row_off[idx] + boff;           // global exclusive prefix
    g_row_off[idx] = running;
    // m2: matrix counts -> segment bases (in-place)
#pragma unroll 7
    for (int c = 0; c < NCHUNK; c++) {
      const unsigned int cnt = g_mat[c * V_NODES + idx];
      g_mat[c * V_NODES + idx] = (unsigned int)running;
      running += (int)cnt;
    }
  }
  if (b == 0 && t == 0) g_row_off[V_NODES] = total;
}

// ---------------- K4: edge scatter — atomic-free, one 8B write/edge ----------
__global__ void edge_scatter_kernel(
    const int* __restrict__ src, const int* __restrict__ dst, int E)
{
  int e = blockIdx.x * blockDim.x + threadIdx.x;
  if (e >= E) return;
  const int d = dst[e], sn = src[e];
  float logit = g_pd[d] + g_ps[sn] + b2f(g_wsmall[OFF_BEDGE]);
  logit = (logit >= 0.f) ? logit : 0.01f * logit;           // LeakyReLU(0.01)
  const float w = __expf(logit);                            // no max-sub: cancels
  const int c = e >> 14;                                    // chunk
  const int pos = (int)g_mat[c * V_NODES + d] + (int)g_rank16[e];
  g_s_pair[pos] = make_int2(sn, __float_as_int(w));
}

// ---------------- K5: aggregation, 4 nodes/block (one per wave) --------------
__global__ __launch_bounds__(256) void aggregate_kernel()
{
  const int v = blockIdx.x * 4 + (threadIdx.x >> 6);   // grid 12500 -> v < 50000
  const int lane = threadIdx.x & 63;                   // lane: cols 2l, 2l+1
  const int beg = g_row_off[v], end = g_row_off[v + 1];
  float accx = 0.f, accy = 0.f, ssum = 0.f;
  int i = beg;
  for (; i + 4 <= end; i += 4) {       // 4 gathers in flight
    const int2 q0 = g_s_pair[i],     q1 = g_s_pair[i + 1],
               q2 = g_s_pair[i + 2], q3 = g_s_pair[i + 3];
    const float w0 = __int_as_float(q0.y), w1 = __int_as_float(q1.y),
                w2 = __int_as_float(q2.y), w3 = __int_as_float(q3.y);
    const unsigned int p0 = *reinterpret_cast<const unsigned int*>(g_hv + q0.x * D_FEAT + lane * 2);
    const unsigned int p1 = *reinterpret_cast<const unsigned int*>(g_hv + q1.x * D_FEAT + lane * 2);
    const unsigned int p2 = *reinterpret_cast<const unsigned int*>(g_hv + q2.x * D_FEAT + lane * 2);
    const unsigned int p3 = *reinterpret_cast<const unsigned int*>(g_hv + q3.x * D_FEAT + lane * 2);
    ssum += (w0 + w1) + (w2 + w3);
    accx += w0 * b2f((unsigned short)(p0 & 0xFFFFu)) + w1 * b2f((unsigned short)(p1 & 0xFFFFu))
          + w2 * b2f((unsigned short)(p2 & 0xFFFFu)) + w3 * b2f((unsigned short)(p3 & 0xFFFFu));
    accy += w0 * b2f((unsigned short)(p0 >> 16)) + w1 * b2f((unsigned short)(p1 >> 16))
          + w2 * b2f((unsigned short)(p2 >> 16)) + w3 * b2f((unsigned short)(p3 >> 16));
  }
  for (; i < end; i++) {
    const int2 q = g_s_pair[i];
    const float w = __int_as_float(q.y);
    ssum += w;
    const unsigned int pair =
        *reinterpret_cast<const unsigned int*>(g_hv + q.x * D_FEAT + lane * 2);
    accx += w * b2f((unsigned short)(pair & 0xFFFFu));
    accy += w * b2f((unsigned short)(pair >> 16));
  }
  const float inv = (end > beg) ? (1.0f / ssum) : 0.0f;     // empty segment -> c=0
  float c0 = accx * inv, c1 = accy * inv;
  c0 = (c0 > 0.f) ? c0 : (__expf(c0) - 1.f);                // elu
  c1 = (c1 > 0.f) ? c1 : (__expf(c1) - 1.f);
  const unsigned int outp = ((unsigned int)f2b(c1) << 16) | (unsigned int)f2b(c0);
  *reinterpret_cast<unsigned int*>(g_ctx + v * D_FEAT + lane * 2) = outp;
}

// ---------------- K6: GRU weight-stationary (R19 form) + XCD-grouped swizzle --
__global__ __launch_bounds__(256, 2) void gru_kernel(const float* __restrict__ xf32,
                                                     float* __restrict__ out)
{
  // XCD-grouping swizzle (mechanism R23-verified): the 2 blocks of a chunk
  // sit on consecutive slots of ONE XCD -> shared A-tile rows hit that L2.
  const int d = blockIdx.x;
  const int x = d & 7;                       // XCD (round-robin dispatch)
  const int s = d >> 3;                      // slot on that XCD [0, 158)
  const int chunk = x + 8 * (s >> 1);        // 2 slots -> same chunk
  if (chunk >= 625) return;                  // block-uniform guard (14 blocks)
  const int half  = s & 1;                   // cg half: 0 -> cg 0..3, 1 -> 4..7
  const int wid   = threadIdx.x >> 6;
  const int lane  = threadIdx.x & 63;
  const int cg    = half * 4 + wid;          // 0..7
  const int col   = lane & 15;
  const int quad  = lane >> 4;
  const int h     = 16 * cg + col;
  const unsigned short* W_ih = g_wsmall + OFF_WIH;
  const unsigned short* W_hh = g_wsmall + OFF_WHH;
  const int isb = g_is_bf16;

  // per-wave constant biases for columns h
  const float br  = b2f(g_wsmall[OFF_BIH + h])       + b2f(g_wsmall[OFF_BHH + h]);
  const float bz  = b2f(g_wsmall[OFF_BIH + 128 + h]) + b2f(g_wsmall[OFF_BHH + 128 + h]);
  const float bn  = b2f(g_wsmall[OFF_BIH + 256 + h]);
  const float bh_ = b2f(g_wsmall[OFF_BHH + 256 + h]);

  // resident B fragments: 24 frags = 96 regs (unified file; launch_bounds(256,2))
  bf16x8 bIHr[4], bHHr[4], bIHz[4], bHHz[4], bIHn[4], bHHn[4];
#pragma unroll
  for (int kk = 0; kk < 4; kk++) {
    const int ko = kk * 32 + quad * 8;
    bIHr[kk] = load_frag(W_ih + h * D_FEAT + ko);
    bHHr[kk] = load_frag(W_hh + h * D_FEAT + ko);
    bIHz[kk] = load_frag(W_ih + (128 + h) * D_FEAT + ko);
    bHHz[kk] = load_frag(W_hh + (128 + h) * D_FEAT + ko);
    bIHn[kk] = load_frag(W_ih + (256 + h) * D_FEAT + ko);
    bHHn[kk] = load_frag(W_hh + (256 + h) * D_FEAT + ko);
  }

  const int t0 = chunk * GCHUNK;
  for (int t = t0; t < t0 + GCHUNK; t++) {
    const int arow = t * 16 + col;
    bf16x8 ax[4], ac[4];
#pragma unroll
    for (int kk = 0; kk < 4; kk++) {
      const int o = arow * D_FEAT + kk * 32 + quad * 8;
      ax[kk] = load_frag(g_xbf + o);
      ac[kk] = load_frag(g_ctx + o);
    }
    // hoist xv loads (issued AFTER the 8 frag loads -> MFMAs start at vmcnt(4),
    // xv latency hides under the 24-MFMA block instead of heading each row)
    float xv[4];
    if (isb) {
#pragma unroll
      for (int r = 0; r < 4; r++)
        xv[r] = b2f(g_xbf[(t * 16 + quad * 4 + r) * D_FEAT + h]);
    } else {
#pragma unroll
      for (int r = 0; r < 4; r++)
        xv[r] = xf32[(t * 16 + quad * 4 + r) * D_FEAT + h];
    }
    f32x4 racc, zacc, niacc, nhacc;
    racc[0]=br;  racc[1]=br;  racc[2]=br;  racc[3]=br;
    zacc[0]=bz;  zacc[1]=bz;  zacc[2]=bz;  zacc[3]=bz;
    niacc[0]=bn; niacc[1]=bn; niacc[2]=bn; niacc[3]=bn;
    nhacc[0]=bh_; nhacc[1]=bh_; nhacc[2]=bh_; nhacc[3]=bh_;
#pragma unroll
    for (int kk = 0; kk < 4; kk++) {
      racc  = __builtin_amdgcn_mfma_f32_16x16x32_bf16(ac[kk], bIHr[kk], racc, 0, 0, 0);
      racc  = __builtin_amdgcn_mfma_f32_16x16x32_bf16(ax[kk], bHHr[kk], racc, 0, 0, 0);
      zacc  = __builtin_amdgcn_mfma_f32_16x16x32_bf16(ac[kk], bIHz[kk], zacc, 0, 0, 0);
      zacc  = __builtin_amdgcn_mfma_f32_16x16x32_bf16(ax[kk], bHHz[kk], zacc, 0, 0, 0);
      niacc = __builtin_amdgcn_mfma_f32_16x16x32_bf16(ac[kk], bIHn[kk], niacc, 0, 0, 0);
      nhacc = __builtin_amdgcn_mfma_f32_16x16x32_bf16(ax[kk], bHHn[kk], nhacc, 0, 0, 0);
    }
#pragma unroll
    for (int r = 0; r < 4; r++) {
      const int vrow = t * 16 + quad * 4 + r;
      const float rg = fast_sigmoid(racc[r]);
      const float zg = fast_sigmoid(zacc[r]);
      const float n  = fast_tanh(niacc[r] + rg * nhacc[r]);
      const float hn = (1.f - zg) * n + zg * xv[r];
      out[vrow * D_FEAT + h] = (hn < 0.f) ? 0.f : hn;  // relu; NaN passes (canary)
    }
  }
}

// ---------------- launch ------------------------------------------------------
extern "C" void kernel_launch(void* const* d_in, const int* in_sizes, int n_in,
                              void* d_out, int out_size, void* d_ws, size_t ws_size,
                              hipStream_t stream)
{
  (void)d_ws; (void)ws_size; (void)out_size;

  // resolve inputs by element count (same-size pairs keep dict order)
  int ix = -1, iWe = -1, ibe = -1, iWp = -1, ibp = -1,
      iWih = -1, iWhh = -1, ibih = -1, ibhh = -1, isrc = -1, idst = -1;
  for (int i = 0; i < n_in; i++) {
    const int s = in_sizes[i];
    if      (s == 6400000) ix = i;
    else if (s == 256)     iWe = i;
    else if (s == 1)       ibe = i;
    else if (s == 16384)   iWp = i;
    else if (s == 128)     ibp = i;
    else if (s == 49152)   { if (iWih < 0) iWih = i; else iWhh = i; }
    else if (s == 384)     { if (ibih < 0) ibih = i; else ibhh = i; }
    else if (s == 800000)  { if (isrc < 0) isrc = i; else idst = i; }
  }
  if (ix < 0 || iWe < 0 || ibe < 0 || iWp < 0 || ibp < 0 || iWih < 0 ||
      iWhh < 0 || ibih < 0 || ibhh < 0 || isrc < 0 || idst < 0) {
    ix = 0; iWe = 1; ibe = 2; iWp = 3; ibp = 4;           // dict-order fallback
    iWih = 5; iWhh = 6; ibih = 7; ibhh = 8; isrc = 9; idst = 10;
  }

  const int* src = (const int*)d_in[isrc];
  const int* dst = (const int*)d_in[idst];
  float* out = (float*)d_out;

  probe_kernel<<<1, 256, 0, stream>>>((const unsigned int*)d_in[ix]);
  conv_fused_kernel<<<CONV_X_BLOCKS + CONV_S_BLOCKS, 256, 0, stream>>>(
      d_in[ix],
      d_in[iWe], d_in[iWp], d_in[iWih], d_in[iWhh],
      d_in[ibe], d_in[ibp], d_in[ibih], d_in[ibhh]);
  np_hist_kernel<<<HISTG + WS_BLOCKS, 256, 0, stream>>>(dst);
  scan_a_kernel<<<SCAN_BLOCKS, 256, 0, stream>>>();
  scan_bcm_kernel<<<SCAN_BLOCKS, 256, 0, stream>>>();
  edge_scatter_kernel<<<HIST_BLOCKS, 256, 0, stream>>>(src, dst, E_EDGES);
  aggregate_kernel<<<V_NODES / 4, 256, 0, stream>>>();
  gru_kernel<<<GRU_BLOCKS, 256, 0, stream>>>((const float*)d_in[ix], out);
}

// Round 15
// 221.984 us; speedup vs baseline: 1.1031x; 1.0537x over previous
//
#include <hip/hip_runtime.h>
#include <hip/hip_bf16.h>

// GNN attention layer. V=50000, E=800000, D=H=128. Inputs f32, OUTPUT f32.
//
// R26: gru latency-floored ~43 us at ideal traffic (R25: FETCH 26.4 MB).
// Per-tile chain: 8 global frag loads -> vmcnt wait (~300-900 cyc; 4 waves
// miss together) -> 24 MFMA -> epilogue = ~5800 cyc. Register prefetch
// failed (R24: regs<->occupancy). Zero-register fix: all 4 waves of a block
// read the SAME A-tiles -> stage via __builtin_amdgcn_global_load_lds
// (async DMA), double-buffered 2x8KB; issue t+1's DMA after reading t's
// frags; __syncthreads' implicit vmcnt(0) drain lands after ~1500 cyc of
// MFMA (cheap). ds_read_b128 with XOR swizzle off^=((row&7)<<4): linear LDS
// dest + inverse-swizzled GLOBAL source + swizzled read (rule #21). xv stays
// a hoisted global load (f32 precision). Single-variable: gru only.
// Rest = R25 (XCD-grouped swizzles, fused scans, int4-ILP LDS hist,
// chunk x range counting sort, atomic-free scatter).

#define V_NODES 50000
#define E_EDGES 800000
#define D_FEAT  128
#define GCHUNK  5             // tiles per chunk (625 chunks x 8 cg = 5000 tasks)
#define WS_BLOCKS 1250        // np: 5000 waves / 4 per block
#define GRU_BLOCKS 1264       // gru: 8 xcds x 158 slots (2 blocks/chunk, guard)

#define NCHUNK  49            // ceil(800000/16384) edge chunks
#define CHUNK_E 16384         // edges per chunk (e >> 14)
#define RANGES  4             // node ranges per chunk
#define NODE_R  12500         // nodes per range (25 KB packed LDS histogram)
#define HISTG   (NCHUNK * RANGES)   // 196 hist blocks
#define SCAN_BLOCKS 196       // ceil(50000/256)

typedef short bf16x8 __attribute__((ext_vector_type(8)));  // 8 bf16 in 4 VGPRs
typedef float f32x4  __attribute__((ext_vector_type(4)));
typedef unsigned short u16x4 __attribute__((ext_vector_type(4)));

// small-tensor bf16 pool element offsets
#define OFF_WEDGE 0
#define OFF_WPROJ 256
#define OFF_WIH   16640
#define OFF_WHH   65792
#define OFF_BEDGE 114944
#define OFF_BPROJ 114945
#define OFF_BIH   115073
#define OFF_BHH   115457
#define SMALL_TOTAL 115841
#define CONV_X_BLOCKS   6250   // 1.6M u16x4 / 256
#define CONV_S_BLOCKS   453
#define HIST_BLOCKS     3125   // 800000/256 (edge scatter grid)

// ---- device-global scratch (~58 MB; immune to ws_size) ----
__device__ int   g_is_bf16;
__device__ float g_pd[V_NODES];
__device__ float g_ps[V_NODES];
__device__ __attribute__((aligned(16))) unsigned int g_mat[NCHUNK * V_NODES]; // counts -> bases
__device__ int   g_row_off[V_NODES + 1];
__device__ int   g_blocksum[SCAN_BLOCKS];
__device__ unsigned short g_rank16[E_EDGES];    // within-chunk rank
__device__ __attribute__((aligned(16))) int2 g_s_pair[E_EDGES];  // {src, bits(w)}
__device__ __attribute__((aligned(16))) unsigned short g_xbf[V_NODES * D_FEAT];
__device__ __attribute__((aligned(16))) unsigned short g_wsmall[SMALL_TOTAL + 15];
__device__ __attribute__((aligned(16))) unsigned short g_hv[V_NODES * D_FEAT];
__device__ __attribute__((aligned(16))) unsigned short g_ctx[V_NODES * D_FEAT];

static __device__ __forceinline__ float b2f(unsigned short u) {
  union { unsigned int i; float f; } v; v.i = ((unsigned int)u) << 16; return v.f;
}
static __device__ __forceinline__ unsigned short f2b(float f) {
  unsigned int i = __float_as_uint(f);
  unsigned int r = (i + 0x7FFFu + ((i >> 16) & 1u)) >> 16;  // RNE (NaN stays NaN)
  return (unsigned short)r;
}
static __device__ __forceinline__ bf16x8 load_frag(const unsigned short* p) {
  return *reinterpret_cast<const bf16x8*>(p);  // 16B-aligned vector load
}
static __device__ __forceinline__ float fast_rcp(float x) {
  return __builtin_amdgcn_rcpf(x);             // v_rcp_f32, ~1 ulp
}
static __device__ __forceinline__ float fast_sigmoid(float x) {
  return fast_rcp(1.f + __expf(-x));           // x<<0: exp->inf, rcp->0. ok
}
static __device__ __forceinline__ float fast_tanh(float y) {
  // 1 - 2/(e^{2y}+1); y>>0: exp->inf, rcp->0 -> 1; y<<0: exp->0 -> -1; NaN->NaN
  return 1.f - 2.f * fast_rcp(__expf(2.f * y) + 1.f);
}
// async global->LDS DMA, 16B per lane; lds ptr is wave-uniform base
static __device__ __forceinline__ void async_copy16(const void* g, void* l) {
  __builtin_amdgcn_global_load_lds(
      (const __attribute__((address_space(1))) void*)g,
      (__attribute__((address_space(3))) void*)l, 16, 0, 0);
}

// ---------------- P: dtype probe on x ----------------------------------------
__global__ void probe_kernel(const unsigned int* __restrict__ x)
{
  __shared__ int cnt;
  if (threadIdx.x == 0) cnt = 0;
  __syncthreads();
  const unsigned int w  = x[threadIdx.x];
  const unsigned int lo = w & 0xFFFFu;
  const unsigned int ex = (lo >> 7) & 0xFFu;
  if (lo != 0u && ex >= 118u && ex <= 132u) atomicAdd(&cnt, 1);
  __syncthreads();
  if (threadIdx.x == 0) g_is_bf16 = (cnt >= 200) ? 1 : 0;
}

// ---------------- C: fused convert-x | convert-smalls ------------------------
__global__ void conv_fused_kernel(
    const void* __restrict__ x,
    const void* p0, const void* p1, const void* p2, const void* p3,
    const void* p4, const void* p5, const void* p6, const void* p7)
{
  const int b = blockIdx.x;
  if (b < CONV_X_BLOCKS) {
    const int t = b * 256 + threadIdx.x;
    if (g_is_bf16) {
      reinterpret_cast<u16x4*>(g_xbf)[t] = reinterpret_cast<const u16x4*>(x)[t];
    } else {
      const float4 v = reinterpret_cast<const float4*>(x)[t];
      u16x4 o; o.x = f2b(v.x); o.y = f2b(v.y); o.z = f2b(v.z); o.w = f2b(v.w);
      reinterpret_cast<u16x4*>(g_xbf)[t] = o;
    }
  } else {
    const int i = (b - CONV_X_BLOCKS) * 256 + threadIdx.x;
    if (i >= SMALL_TOTAL) return;
    const int offs[9] = {OFF_WEDGE, OFF_WPROJ, OFF_WIH, OFF_WHH,
                         OFF_BEDGE, OFF_BPROJ, OFF_BIH, OFF_BHH, SMALL_TOTAL};
    const void* ps[8] = {p0, p1, p2, p3, p4, p5, p6, p7};
    int r = 0;
#pragma unroll
    for (int k = 0; k < 8; k++) if (i >= offs[k]) r = k;
    const int j = i - offs[r];
    g_wsmall[i] = g_is_bf16
        ? reinterpret_cast<const unsigned short*>(ps[r])[j]
        : f2b(reinterpret_cast<const float*>(ps[r])[j]);
  }
}

// ---------------- K1: hist(c,r) int4-ILP LDS + node_pre ----------------------
__global__ __launch_bounds__(256, 2) void np_hist_kernel(const int* __restrict__ dst)
{
  __shared__ unsigned int hloc[NODE_R / 2];  // 25 KB; 2 node counters per word
  const int b = blockIdx.x;
  if (b < HISTG) {                           // ---- chunk x range histogram ----
    const int c  = b >> 2;                   // chunk [0,49)
    const int r0 = (b & 3) * NODE_R;         // range base node
    for (int i = threadIdx.x; i < NODE_R / 2; i += 256) hloc[i] = 0u;
    __syncthreads();
    const int ebase = c * CHUNK_E;
    const int ecnt  = min(CHUNK_E, E_EDGES - ebase);   // always multiple of 4
    const int4* dst4 = reinterpret_cast<const int4*>(dst + ebase);
    const int n4 = ecnt >> 2;
    for (int i = threadIdx.x; i < n4; i += 256) {
      const int4 d4 = dst4[i];               // 4 edges per thread per iter
      const int e0 = ebase + (i << 2);
      const unsigned int rx = (unsigned int)(d4.x - r0);
      const unsigned int ry = (unsigned int)(d4.y - r0);
      const unsigned int rz = (unsigned int)(d4.z - r0);
      const unsigned int rw = (unsigned int)(d4.w - r0);
      if (rx < (unsigned int)NODE_R) {       // 4 independent atomics pipeline
        const unsigned int sh = (rx & 1u) << 4;
        const unsigned int old = atomicAdd(&hloc[rx >> 1], 1u << sh);
        g_rank16[e0] = (unsigned short)((old >> sh) & 0xFFFFu);
      }
      if (ry < (unsigned int)NODE_R) {
        const unsigned int sh = (ry & 1u) << 4;
        const unsigned int old = atomicAdd(&hloc[ry >> 1], 1u << sh);
        g_rank16[e0 + 1] = (unsigned short)((old >> sh) & 0xFFFFu);
      }
      if (rz < (unsigned int)NODE_R) {
        const unsigned int sh = (rz & 1u) << 4;
        const unsigned int old = atomicAdd(&hloc[rz >> 1], 1u << sh);
        g_rank16[e0 + 2] = (unsigned short)((old >> sh) & 0xFFFFu);
      }
      if (rw < (unsigned int)NODE_R) {
        const unsigned int sh = (rw & 1u) << 4;
        const unsigned int old = atomicAdd(&hloc[rw >> 1], 1u << sh);
        g_rank16[e0 + 3] = (unsigned short)((old >> sh) & 0xFFFFu);
      }
    }
    __syncthreads();
    // vectorized writeout: one hloc word -> uint2 {lo count, hi count}
    uint2* mout = reinterpret_cast<uint2*>(&g_mat[c * V_NODES + r0]);
    for (int i = threadIdx.x; i < NODE_R / 2; i += 256) {
      const unsigned int w = hloc[i];
      mout[i] = make_uint2(w & 0xFFFFu, w >> 16);
    }
    return;
  }
  // ---- node_pre: wave-task g -> col-group cg, tile chunk ----
  const int g     = (b - HISTG) * 4 + (threadIdx.x >> 6);
  const int lane  = threadIdx.x & 63;
  const int cg    = g & 7;
  const int chunk = g >> 3;                  // [0, 625)
  const int col   = lane & 15;
  const int quad  = lane >> 4;
  const int h     = 16 * cg + col;

  // resident B fragments: W_proj rows [16cg, 16cg+16)
  bf16x8 bw[4];
#pragma unroll
  for (int kk = 0; kk < 4; kk++)
    bw[kk] = load_frag(g_wsmall + OFF_WPROJ + h * D_FEAT + kk * 32 + quad * 8);
  // cg 0 also owns the edge projections (cols 0/1 of W_edge)
  bf16x8 be[4];
#pragma unroll
  for (int kk = 0; kk < 4; kk++) { be[kk] = bf16x8{0,0,0,0,0,0,0,0}; }
  if (cg == 0 && col < 2) {
#pragma unroll
    for (int kk = 0; kk < 4; kk++)
      be[kk] = load_frag(g_wsmall + OFF_WEDGE + col * D_FEAT + kk * 32 + quad * 8);
  }
  const float bp = b2f(g_wsmall[OFF_BPROJ + h]);

  const int t0 = chunk * GCHUNK;
  bf16x8 a[4];
#pragma unroll
  for (int kk = 0; kk < 4; kk++)
    a[kk] = load_frag(g_xbf + (t0 * 16 + col) * D_FEAT + kk * 32 + quad * 8);
  for (int t = t0; t < t0 + GCHUNK; t++) {
    // prefetch next tile's A while current tile computes (uniform clamp)
    const int tn = (t + 1 < t0 + GCHUNK) ? t + 1 : t;
    bf16x8 na[4];
#pragma unroll
    for (int kk = 0; kk < 4; kk++)
      na[kk] = load_frag(g_xbf + (tn * 16 + col) * D_FEAT + kk * 32 + quad * 8);
    f32x4 acc; acc[0]=0.f; acc[1]=0.f; acc[2]=0.f; acc[3]=0.f;
#pragma unroll
    for (int kk = 0; kk < 4; kk++)
      acc = __builtin_amdgcn_mfma_f32_16x16x32_bf16(a[kk], bw[kk], acc, 0, 0, 0);
#pragma unroll
    for (int r = 0; r < 4; r++)
      g_hv[(t * 16 + quad * 4 + r) * D_FEAT + h] = f2b(acc[r] + bp);
    if (cg == 0) {
      f32x4 acce; acce[0]=0.f; acce[1]=0.f; acce[2]=0.f; acce[3]=0.f;
#pragma unroll
      for (int kk = 0; kk < 4; kk++)
        acce = __builtin_amdgcn_mfma_f32_16x16x32_bf16(a[kk], be[kk], acce, 0, 0, 0);
      if (col == 0) {
#pragma unroll
        for (int r = 0; r < 4; r++) g_pd[t * 16 + quad * 4 + r] = acce[r];
      } else if (col == 1) {
#pragma unroll
        for (int r = 0; r < 4; r++) g_ps[t * 16 + quad * 4 + r] = acce[r];
      }
    }
#pragma unroll
    for (int kk = 0; kk < 4; kk++) a[kk] = na[kk];
  }
}

// ---------------- K3a: column-sum over chunks + block-local scan --------------
__global__ __launch_bounds__(256) void scan_a_kernel()
{
  __shared__ int lds[256];
  const int b = blockIdx.x, t = threadIdx.x;
  const int idx = b * 256 + t;
  int v = 0;
  if (idx < V_NODES) {
#pragma unroll 7
    for (int c = 0; c < NCHUNK; c++) v += (int)g_mat[c * V_NODES + idx];
  }
  lds[t] = v;
  __syncthreads();
  for (int off = 1; off < 256; off <<= 1) {
    int tmp = (t >= off) ? lds[t - off] : 0;
    __syncthreads();
    lds[t] += tmp;
    __syncthreads();
  }
  if (idx < V_NODES) g_row_off[idx] = lds[t] - v;   // local exclusive prefix
  if (t == 255) g_blocksum[b] = lds[255];
}

// ---------------- K3b: fused blocksum-scan + offset-add + m2 base walk --------
__global__ __launch_bounds__(256) void scan_bcm_kernel()
{
  __shared__ int lds[256];
  const int b = blockIdx.x, t = threadIdx.x;       // 196 blocks
  // every block redundantly scans the 196 block sums (trivial)
  const int v = (t < SCAN_BLOCKS) ? g_blocksum[t] : 0;
  lds[t] = v;
  __syncthreads();
  for (int off = 1; off < 256; off <<= 1) {
    int tmp = (t >= off) ? lds[t - off] : 0;
    __syncthreads();
    lds[t] += tmp;
    __syncthreads();
  }
  const int total = lds[255];                      // = E
  const int boff  = (b == 0) ? 0 : lds[b - 1];     // exclusive offset of block b
  const int idx = b * 256 + t;
  if (idx < V_NODES) {
    int running = g_row_off[idx] + boff;           // global exclusive prefix
    g_row_off[idx] = running;
    // m2: matrix counts -> segment bases (in-place)
#pragma unroll 7
    for (int c = 0; c < NCHUNK; c++) {
      const unsigned int cnt = g_mat[c * V_NODES + idx];
      g_mat[c * V_NODES + idx] = (unsigned int)running;
      running += (int)cnt;
    }
  }
  if (b == 0 && t == 0) g_row_off[V_NODES] = total;
}

// ---------------- K4: edge scatter — atomic-free, one 8B write/edge ----------
__global__ void edge_scatter_kernel(
    const int* __restrict__ src, const int* __restrict__ dst, int E)
{
  int e = blockIdx.x * blockDim.x + threadIdx.x;
  if (e >= E) return;
  const int d = dst[e], sn = src[e];
  float logit = g_pd[d] + g_ps[sn] + b2f(g_wsmall[OFF_BEDGE]);
  logit = (logit >= 0.f) ? logit : 0.01f * logit;           // LeakyReLU(0.01)
  const float w = __expf(logit);                            // no max-sub: cancels
  const int c = e >> 14;                                    // chunk
  const int pos = (int)g_mat[c * V_NODES + d] + (int)g_rank16[e];
  g_s_pair[pos] = make_int2(sn, __float_as_int(w));
}

// ---------------- K5: aggregation, 4 nodes/block (one per wave) --------------
__global__ __launch_bounds__(256) void aggregate_kernel()
{
  const int v = blockIdx.x * 4 + (threadIdx.x >> 6);   // grid 12500 -> v < 50000
  const int lane = threadIdx.x & 63;                   // lane: cols 2l, 2l+1
  const int beg = g_row_off[v], end = g_row_off[v + 1];
  float accx = 0.f, accy = 0.f, ssum = 0.f;
  int i = beg;
  for (; i + 4 <= end; i += 4) {       // 4 gathers in flight
    const int2 q0 = g_s_pair[i],     q1 = g_s_pair[i + 1],
               q2 = g_s_pair[i + 2], q3 = g_s_pair[i + 3];
    const float w0 = __int_as_float(q0.y), w1 = __int_as_float(q1.y),
                w2 = __int_as_float(q2.y), w3 = __int_as_float(q3.y);
    const unsigned int p0 = *reinterpret_cast<const unsigned int*>(g_hv + q0.x * D_FEAT + lane * 2);
    const unsigned int p1 = *reinterpret_cast<const unsigned int*>(g_hv + q1.x * D_FEAT + lane * 2);
    const unsigned int p2 = *reinterpret_cast<const unsigned int*>(g_hv + q2.x * D_FEAT + lane * 2);
    const unsigned int p3 = *reinterpret_cast<const unsigned int*>(g_hv + q3.x * D_FEAT + lane * 2);
    ssum += (w0 + w1) + (w2 + w3);
    accx += w0 * b2f((unsigned short)(p0 & 0xFFFFu)) + w1 * b2f((unsigned short)(p1 & 0xFFFFu))
          + w2 * b2f((unsigned short)(p2 & 0xFFFFu)) + w3 * b2f((unsigned short)(p3 & 0xFFFFu));
    accy += w0 * b2f((unsigned short)(p0 >> 16)) + w1 * b2f((unsigned short)(p1 >> 16))
          + w2 * b2f((unsigned short)(p2 >> 16)) + w3 * b2f((unsigned short)(p3 >> 16));
  }
  for (; i < end; i++) {
    const int2 q = g_s_pair[i];
    const float w = __int_as_float(q.y);
    ssum += w;
    const unsigned int pair =
        *reinterpret_cast<const unsigned int*>(g_hv + q.x * D_FEAT + lane * 2);
    accx += w * b2f((unsigned short)(pair & 0xFFFFu));
    accy += w * b2f((unsigned short)(pair >> 16));
  }
  const float inv = (end > beg) ? (1.0f / ssum) : 0.0f;     // empty segment -> c=0
  float c0 = accx * inv, c1 = accy * inv;
  c0 = (c0 > 0.f) ? c0 : (__expf(c0) - 1.f);                // elu
  c1 = (c1 > 0.f) ? c1 : (__expf(c1) - 1.f);
  const unsigned int outp = ((unsigned int)f2b(c1) << 16) | (unsigned int)f2b(c0);
  *reinterpret_cast<unsigned int*>(g_ctx + v * D_FEAT + lane * 2) = outp;
}

// ---------------- K6: GRU weight-stationary + XCD swizzle + LDS DMA pipeline --
__global__ __launch_bounds__(256, 2) void gru_kernel(const float* __restrict__ xf32,
                                                     float* __restrict__ out)
{
  // XCD-grouping swizzle (R23/R25-verified): 2 blocks of a chunk on one XCD.
  const int d = blockIdx.x;
  const int x = d & 7;                       // XCD (round-robin dispatch)
  const int s = d >> 3;                      // slot on that XCD [0, 158)
  const int chunk = x + 8 * (s >> 1);        // 2 slots -> same chunk
  if (chunk >= 625) return;                  // block-uniform guard (14 blocks)
  // double-buffered A-tile staging: [buf][x:0-4K | ctx:4K-8K], linear layout,
  // values pre-permuted at stage so swizzled ds_read is conflict-free.
  __shared__ __attribute__((aligned(16))) char lds_s[2][8192];
  const int half  = s & 1;                   // cg half: 0 -> cg 0..3, 1 -> 4..7
  const int wid   = threadIdx.x >> 6;
  const int lane  = threadIdx.x & 63;
  const int cg    = half * 4 + wid;          // 0..7
  const int col   = lane & 15;
  const int quad  = lane >> 4;
  const int h     = 16 * cg + col;
  const unsigned short* W_ih = g_wsmall + OFF_WIH;
  const unsigned short* W_hh = g_wsmall + OFF_WHH;
  const int isb = g_is_bf16;

  // per-wave constant biases for columns h
  const float br  = b2f(g_wsmall[OFF_BIH + h])       + b2f(g_wsmall[OFF_BHH + h]);
  const float bz  = b2f(g_wsmall[OFF_BIH + 128 + h]) + b2f(g_wsmall[OFF_BHH + 128 + h]);
  const float bn  = b2f(g_wsmall[OFF_BIH + 256 + h]);
  const float bh_ = b2f(g_wsmall[OFF_BHH + 256 + h]);

  // resident B fragments: 24 frags = 96 regs (unified file; launch_bounds(256,2))
  bf16x8 bIHr[4], bHHr[4], bIHz[4], bHHz[4], bIHn[4], bHHn[4];
#pragma unroll
  for (int kk = 0; kk < 4; kk++) {
    const int ko = kk * 32 + quad * 8;
    bIHr[kk] = load_frag(W_ih + h * D_FEAT + ko);
    bHHr[kk] = load_frag(W_hh + h * D_FEAT + ko);
    bIHz[kk] = load_frag(W_ih + (128 + h) * D_FEAT + ko);
    bHHz[kk] = load_frag(W_hh + (128 + h) * D_FEAT + ko);
    bIHn[kk] = load_frag(W_ih + (256 + h) * D_FEAT + ko);
    bHHn[kk] = load_frag(W_hh + (256 + h) * D_FEAT + ko);
  }

  // staging addresses: thread's linear dest offset o in a 4KB tile; the value
  // placed there comes from global offset o ^ ((row&7)<<4) (involution), so a
  // swizzled ds_read returns the logical element (rule #21: both sides).
  const int o_lin = wid * 1024 + lane * 16;                 // dest offset
  const int o_src = o_lin ^ (((o_lin >> 8) & 7) << 4);      // swizzled source
  const char* xbf_b = reinterpret_cast<const char*>(g_xbf);
  const char* ctx_b = reinterpret_cast<const char*>(g_ctx);

  const int t0 = chunk * GCHUNK;
  // prologue: issue DMA for tile t0 into buf 0
  async_copy16(xbf_b + (size_t)t0 * 4096 + o_src, &lds_s[0][wid * 1024]);
  async_copy16(ctx_b + (size_t)t0 * 4096 + o_src, &lds_s[0][4096 + wid * 1024]);

  for (int i = 0; i < GCHUNK; i++) {
    const int t = t0 + i;
    const int buf = i & 1;
    __syncthreads();   // implicit vmcnt(0) drain: buf's DMA complete + visible
    // ds_read frags from staged tile (swizzled, conflict-light)
    bf16x8 ax[4], ac[4];
#pragma unroll
    for (int kk = 0; kk < 4; kk++) {
      const int phys = (col * 256 + kk * 64 + quad * 16) ^ ((col & 7) << 4);
      ax[kk] = *reinterpret_cast<const bf16x8*>(&lds_s[buf][phys]);
      ac[kk] = *reinterpret_cast<const bf16x8*>(&lds_s[buf][4096 + phys]);
    }
    // issue next tile's DMA now (zero-register prefetch; covered by MFMA)
    if (i + 1 < GCHUNK) {
      async_copy16(xbf_b + (size_t)(t + 1) * 4096 + o_src,
                   &lds_s[buf ^ 1][wid * 1024]);
      async_copy16(ctx_b + (size_t)(t + 1) * 4096 + o_src,
                   &lds_s[buf ^ 1][4096 + wid * 1024]);
    }
    // hoisted xv global loads (keep f32 precision path; hidden under MFMAs)
    float xv[4];
    if (isb) {
#pragma unroll
      for (int r = 0; r < 4; r++)
        xv[r] = b2f(g_xbf[(t * 16 + quad * 4 + r) * D_FEAT + h]);
    } else {
#pragma unroll
      for (int r = 0; r < 4; r++)
        xv[r] = xf32[(t * 16 + quad * 4 + r) * D_FEAT + h];
    }
    f32x4 racc, zacc, niacc, nhacc;
    racc[0]=br;  racc[1]=br;  racc[2]=br;  racc[3]=br;
    zacc[0]=bz;  zacc[1]=bz;  zacc[2]=bz;  zacc[3]=bz;
    niacc[0]=bn; niacc[1]=bn; niacc[2]=bn; niacc[3]=bn;
    nhacc[0]=bh_; nhacc[1]=bh_; nhacc[2]=bh_; nhacc[3]=bh_;
#pragma unroll
    for (int kk = 0; kk < 4; kk++) {
      racc  = __builtin_amdgcn_mfma_f32_16x16x32_bf16(ac[kk], bIHr[kk], racc, 0, 0, 0);
      racc  = __builtin_amdgcn_mfma_f32_16x16x32_bf16(ax[kk], bHHr[kk], racc, 0, 0, 0);
      zacc  = __builtin_amdgcn_mfma_f32_16x16x32_bf16(ac[kk], bIHz[kk], zacc, 0, 0, 0);
      zacc  = __builtin_amdgcn_mfma_f32_16x16x32_bf16(ax[kk], bHHz[kk], zacc, 0, 0, 0);
      niacc = __builtin_amdgcn_mfma_f32_16x16x32_bf16(ac[kk], bIHn[kk], niacc, 0, 0, 0);
      nhacc = __builtin_amdgcn_mfma_f32_16x16x32_bf16(ax[kk], bHHn[kk], nhacc, 0, 0, 0);
    }
#pragma unroll
    for (int r = 0; r < 4; r++) {
      const int vrow = t * 16 + quad * 4 + r;
      const float rg = fast_sigmoid(racc[r]);
      const float zg = fast_sigmoid(zacc[r]);
      const float n  = fast_tanh(niacc[r] + rg * nhacc[r]);
      const float hn = (1.f - zg) * n + zg * xv[r];
      out[vrow * D_FEAT + h] = (hn < 0.f) ? 0.f : hn;  // relu; NaN passes (canary)
    }
  }
}

// ---------------- launch ------------------------------------------------------
extern "C" void kernel_launch(void* const* d_in, const int* in_sizes, int n_in,
                              void* d_out, int out_size, void* d_ws, size_t ws_size,
                              hipStream_t stream)
{
  (void)d_ws; (void)ws_size; (void)out_size;

  // resolve inputs by element count (same-size pairs keep dict order)
  int ix = -1, iWe = -1, ibe = -1, iWp = -1, ibp = -1,
      iWih = -1, iWhh = -1, ibih = -1, ibhh = -1, isrc = -1, idst = -1;
  for (int i = 0; i < n_in; i++) {
    const int s = in_sizes[i];
    if      (s == 6400000) ix = i;
    else if (s == 256)     iWe = i;
    else if (s == 1)       ibe = i;
    else if (s == 16384)   iWp = i;
    else if (s == 128)     ibp = i;
    else if (s == 49152)   { if (iWih < 0) iWih = i; else iWhh = i; }
    else if (s == 384)     { if (ibih < 0) ibih = i; else ibhh = i; }
    else if (s == 800000)  { if (isrc < 0) isrc = i; else idst = i; }
  }
  if (ix < 0 || iWe < 0 || ibe < 0 || iWp < 0 || ibp < 0 || iWih < 0 ||
      iWhh < 0 || ibih < 0 || ibhh < 0 || isrc < 0 || idst < 0) {
    ix = 0; iWe = 1; ibe = 2; iWp = 3; ibp = 4;           // dict-order fallback
    iWih = 5; iWhh = 6; ibih = 7; ibhh = 8; isrc = 9; idst = 10;
  }

  const int* src = (const int*)d_in[isrc];
  const int* dst = (const int*)d_in[idst];
  float* out = (float*)d_out;

  probe_kernel<<<1, 256, 0, stream>>>((const unsigned int*)d_in[ix]);
  conv_fused_kernel<<<CONV_X_BLOCKS + CONV_S_BLOCKS, 256, 0, stream>>>(
      d_in[ix],
      d_in[iWe], d_in[iWp], d_in[iWih], d_in[iWhh],
      d_in[ibe], d_in[ibp], d_in[ibih], d_in[ibhh]);
  np_hist_kernel<<<HISTG + WS_BLOCKS, 256, 0, stream>>>(dst);
  scan_a_kernel<<<SCAN_BLOCKS, 256, 0, stream>>>();
  scan_bcm_kernel<<<SCAN_BLOCKS, 256, 0, stream>>>();
  edge_scatter_kernel<<<HIST_BLOCKS, 256, 0, stream>>>(src, dst, E_EDGES);
  aggregate_kernel<<<V_NODES / 4, 256, 0, stream>>>();
  gru_kernel<<<GRU_BLOCKS, 256, 0, stream>>>((const float*)d_in[ix], out);
}

// Round 16
// 217.505 us; speedup vs baseline: 1.1258x; 1.0206x over previous
//
#include <hip/hip_runtime.h>
#include <hip/hip_bf16.h>

// GNN attention layer. V=50000, E=800000, D=H=128. Inputs f32, OUTPUT f32.
//
// R27: R26's LDS-DMA pipeline removed gru from top-5 (total 234->222).
// New pole: aggregate (41.7 us; FETCH 109 MB ~= compulsory after L2 reuse,
// 3.0 TB/s, VALU 40%, Mfma 0). Dur = traffic/rate exactly -> gather-bound.
// Little's law: need ~110 lines in flight/CU at ~600cyc; current 4-deep
// unroll x ~19 waves gives marginal depth -> IN-FLIGHT DEPTH, not fabric,
// is the suspected limit. Fix: deepen aggregate to 8 edges/iter (8 s_pair
// loads then 8 row gathers in flight; VGPR 16->~40, occupancy unaffected);
// keep 4-deep + scalar tails. Falsifier: unchanged dur -> fabric ceiling at
// near-compulsory traffic -> structural floor. Rest = R26 (gru LDS-DMA +
// XCD swizzles, fused scans, int4-ILP LDS hist, counting sort, atomic-free
// scatter).

#define V_NODES 50000
#define E_EDGES 800000
#define D_FEAT  128
#define GCHUNK  5             // tiles per chunk (625 chunks x 8 cg = 5000 tasks)
#define WS_BLOCKS 1250        // np: 5000 waves / 4 per block
#define GRU_BLOCKS 1264       // gru: 8 xcds x 158 slots (2 blocks/chunk, guard)

#define NCHUNK  49            // ceil(800000/16384) edge chunks
#define CHUNK_E 16384         // edges per chunk (e >> 14)
#define RANGES  4             // node ranges per chunk
#define NODE_R  12500         // nodes per range (25 KB packed LDS histogram)
#define HISTG   (NCHUNK * RANGES)   // 196 hist blocks
#define SCAN_BLOCKS 196       // ceil(50000/256)

typedef short bf16x8 __attribute__((ext_vector_type(8)));  // 8 bf16 in 4 VGPRs
typedef float f32x4  __attribute__((ext_vector_type(4)));
typedef unsigned short u16x4 __attribute__((ext_vector_type(4)));

// small-tensor bf16 pool element offsets
#define OFF_WEDGE 0
#define OFF_WPROJ 256
#define OFF_WIH   16640
#define OFF_WHH   65792
#define OFF_BEDGE 114944
#define OFF_BPROJ 114945
#define OFF_BIH   115073
#define OFF_BHH   115457
#define SMALL_TOTAL 115841
#define CONV_X_BLOCKS   6250   // 1.6M u16x4 / 256
#define CONV_S_BLOCKS   453
#define HIST_BLOCKS     3125   // 800000/256 (edge scatter grid)

// ---- device-global scratch (~58 MB; immune to ws_size) ----
__device__ int   g_is_bf16;
__device__ float g_pd[V_NODES];
__device__ float g_ps[V_NODES];
__device__ __attribute__((aligned(16))) unsigned int g_mat[NCHUNK * V_NODES]; // counts -> bases
__device__ int   g_row_off[V_NODES + 1];
__device__ int   g_blocksum[SCAN_BLOCKS];
__device__ unsigned short g_rank16[E_EDGES];    // within-chunk rank
__device__ __attribute__((aligned(16))) int2 g_s_pair[E_EDGES];  // {src, bits(w)}
__device__ __attribute__((aligned(16))) unsigned short g_xbf[V_NODES * D_FEAT];
__device__ __attribute__((aligned(16))) unsigned short g_wsmall[SMALL_TOTAL + 15];
__device__ __attribute__((aligned(16))) unsigned short g_hv[V_NODES * D_FEAT];
__device__ __attribute__((aligned(16))) unsigned short g_ctx[V_NODES * D_FEAT];

static __device__ __forceinline__ float b2f(unsigned short u) {
  union { unsigned int i; float f; } v; v.i = ((unsigned int)u) << 16; return v.f;
}
static __device__ __forceinline__ unsigned short f2b(float f) {
  unsigned int i = __float_as_uint(f);
  unsigned int r = (i + 0x7FFFu + ((i >> 16) & 1u)) >> 16;  // RNE (NaN stays NaN)
  return (unsigned short)r;
}
static __device__ __forceinline__ bf16x8 load_frag(const unsigned short* p) {
  return *reinterpret_cast<const bf16x8*>(p);  // 16B-aligned vector load
}
static __device__ __forceinline__ float fast_rcp(float x) {
  return __builtin_amdgcn_rcpf(x);             // v_rcp_f32, ~1 ulp
}
static __device__ __forceinline__ float fast_sigmoid(float x) {
  return fast_rcp(1.f + __expf(-x));           // x<<0: exp->inf, rcp->0. ok
}
static __device__ __forceinline__ float fast_tanh(float y) {
  // 1 - 2/(e^{2y}+1); y>>0: exp->inf, rcp->0 -> 1; y<<0: exp->0 -> -1; NaN->NaN
  return 1.f - 2.f * fast_rcp(__expf(2.f * y) + 1.f);
}
// async global->LDS DMA, 16B per lane; lds ptr is wave-uniform base
static __device__ __forceinline__ void async_copy16(const void* g, void* l) {
  __builtin_amdgcn_global_load_lds(
      (const __attribute__((address_space(1))) void*)g,
      (__attribute__((address_space(3))) void*)l, 16, 0, 0);
}

// ---------------- P: dtype probe on x ----------------------------------------
__global__ void probe_kernel(const unsigned int* __restrict__ x)
{
  __shared__ int cnt;
  if (threadIdx.x == 0) cnt = 0;
  __syncthreads();
  const unsigned int w  = x[threadIdx.x];
  const unsigned int lo = w & 0xFFFFu;
  const unsigned int ex = (lo >> 7) & 0xFFu;
  if (lo != 0u && ex >= 118u && ex <= 132u) atomicAdd(&cnt, 1);
  __syncthreads();
  if (threadIdx.x == 0) g_is_bf16 = (cnt >= 200) ? 1 : 0;
}

// ---------------- C: fused convert-x | convert-smalls ------------------------
__global__ void conv_fused_kernel(
    const void* __restrict__ x,
    const void* p0, const void* p1, const void* p2, const void* p3,
    const void* p4, const void* p5, const void* p6, const void* p7)
{
  const int b = blockIdx.x;
  if (b < CONV_X_BLOCKS) {
    const int t = b * 256 + threadIdx.x;
    if (g_is_bf16) {
      reinterpret_cast<u16x4*>(g_xbf)[t] = reinterpret_cast<const u16x4*>(x)[t];
    } else {
      const float4 v = reinterpret_cast<const float4*>(x)[t];
      u16x4 o; o.x = f2b(v.x); o.y = f2b(v.y); o.z = f2b(v.z); o.w = f2b(v.w);
      reinterpret_cast<u16x4*>(g_xbf)[t] = o;
    }
  } else {
    const int i = (b - CONV_X_BLOCKS) * 256 + threadIdx.x;
    if (i >= SMALL_TOTAL) return;
    const int offs[9] = {OFF_WEDGE, OFF_WPROJ, OFF_WIH, OFF_WHH,
                         OFF_BEDGE, OFF_BPROJ, OFF_BIH, OFF_BHH, SMALL_TOTAL};
    const void* ps[8] = {p0, p1, p2, p3, p4, p5, p6, p7};
    int r = 0;
#pragma unroll
    for (int k = 0; k < 8; k++) if (i >= offs[k]) r = k;
    const int j = i - offs[r];
    g_wsmall[i] = g_is_bf16
        ? reinterpret_cast<const unsigned short*>(ps[r])[j]
        : f2b(reinterpret_cast<const float*>(ps[r])[j]);
  }
}

// ---------------- K1: hist(c,r) int4-ILP LDS + node_pre ----------------------
__global__ __launch_bounds__(256, 2) void np_hist_kernel(const int* __restrict__ dst)
{
  __shared__ unsigned int hloc[NODE_R / 2];  // 25 KB; 2 node counters per word
  const int b = blockIdx.x;
  if (b < HISTG) {                           // ---- chunk x range histogram ----
    const int c  = b >> 2;                   // chunk [0,49)
    const int r0 = (b & 3) * NODE_R;         // range base node
    for (int i = threadIdx.x; i < NODE_R / 2; i += 256) hloc[i] = 0u;
    __syncthreads();
    const int ebase = c * CHUNK_E;
    const int ecnt  = min(CHUNK_E, E_EDGES - ebase);   // always multiple of 4
    const int4* dst4 = reinterpret_cast<const int4*>(dst + ebase);
    const int n4 = ecnt >> 2;
    for (int i = threadIdx.x; i < n4; i += 256) {
      const int4 d4 = dst4[i];               // 4 edges per thread per iter
      const int e0 = ebase + (i << 2);
      const unsigned int rx = (unsigned int)(d4.x - r0);
      const unsigned int ry = (unsigned int)(d4.y - r0);
      const unsigned int rz = (unsigned int)(d4.z - r0);
      const unsigned int rw = (unsigned int)(d4.w - r0);
      if (rx < (unsigned int)NODE_R) {       // 4 independent atomics pipeline
        const unsigned int sh = (rx & 1u) << 4;
        const unsigned int old = atomicAdd(&hloc[rx >> 1], 1u << sh);
        g_rank16[e0] = (unsigned short)((old >> sh) & 0xFFFFu);
      }
      if (ry < (unsigned int)NODE_R) {
        const unsigned int sh = (ry & 1u) << 4;
        const unsigned int old = atomicAdd(&hloc[ry >> 1], 1u << sh);
        g_rank16[e0 + 1] = (unsigned short)((old >> sh) & 0xFFFFu);
      }
      if (rz < (unsigned int)NODE_R) {
        const unsigned int sh = (rz & 1u) << 4;
        const unsigned int old = atomicAdd(&hloc[rz >> 1], 1u << sh);
        g_rank16[e0 + 2] = (unsigned short)((old >> sh) & 0xFFFFu);
      }
      if (rw < (unsigned int)NODE_R) {
        const unsigned int sh = (rw & 1u) << 4;
        const unsigned int old = atomicAdd(&hloc[rw >> 1], 1u << sh);
        g_rank16[e0 + 3] = (unsigned short)((old >> sh) & 0xFFFFu);
      }
    }
    __syncthreads();
    // vectorized writeout: one hloc word -> uint2 {lo count, hi count}
    uint2* mout = reinterpret_cast<uint2*>(&g_mat[c * V_NODES + r0]);
    for (int i = threadIdx.x; i < NODE_R / 2; i += 256) {
      const unsigned int w = hloc[i];
      mout[i] = make_uint2(w & 0xFFFFu, w >> 16);
    }
    return;
  }
  // ---- node_pre: wave-task g -> col-group cg, tile chunk ----
  const int g     = (b - HISTG) * 4 + (threadIdx.x >> 6);
  const int lane  = threadIdx.x & 63;
  const int cg    = g & 7;
  const int chunk = g >> 3;                  // [0, 625)
  const int col   = lane & 15;
  const int quad  = lane >> 4;
  const int h     = 16 * cg + col;

  // resident B fragments: W_proj rows [16cg, 16cg+16)
  bf16x8 bw[4];
#pragma unroll
  for (int kk = 0; kk < 4; kk++)
    bw[kk] = load_frag(g_wsmall + OFF_WPROJ + h * D_FEAT + kk * 32 + quad * 8);
  // cg 0 also owns the edge projections (cols 0/1 of W_edge)
  bf16x8 be[4];
#pragma unroll
  for (int kk = 0; kk < 4; kk++) { be[kk] = bf16x8{0,0,0,0,0,0,0,0}; }
  if (cg == 0 && col < 2) {
#pragma unroll
    for (int kk = 0; kk < 4; kk++)
      be[kk] = load_frag(g_wsmall + OFF_WEDGE + col * D_FEAT + kk * 32 + quad * 8);
  }
  const float bp = b2f(g_wsmall[OFF_BPROJ + h]);

  const int t0 = chunk * GCHUNK;
  bf16x8 a[4];
#pragma unroll
  for (int kk = 0; kk < 4; kk++)
    a[kk] = load_frag(g_xbf + (t0 * 16 + col) * D_FEAT + kk * 32 + quad * 8);
  for (int t = t0; t < t0 + GCHUNK; t++) {
    // prefetch next tile's A while current tile computes (uniform clamp)
    const int tn = (t + 1 < t0 + GCHUNK) ? t + 1 : t;
    bf16x8 na[4];
#pragma unroll
    for (int kk = 0; kk < 4; kk++)
      na[kk] = load_frag(g_xbf + (tn * 16 + col) * D_FEAT + kk * 32 + quad * 8);
    f32x4 acc; acc[0]=0.f; acc[1]=0.f; acc[2]=0.f; acc[3]=0.f;
#pragma unroll
    for (int kk = 0; kk < 4; kk++)
      acc = __builtin_amdgcn_mfma_f32_16x16x32_bf16(a[kk], bw[kk], acc, 0, 0, 0);
#pragma unroll
    for (int r = 0; r < 4; r++)
      g_hv[(t * 16 + quad * 4 + r) * D_FEAT + h] = f2b(acc[r] + bp);
    if (cg == 0) {
      f32x4 acce; acce[0]=0.f; acce[1]=0.f; acce[2]=0.f; acce[3]=0.f;
#pragma unroll
      for (int kk = 0; kk < 4; kk++)
        acce = __builtin_amdgcn_mfma_f32_16x16x32_bf16(a[kk], be[kk], acce, 0, 0, 0);
      if (col == 0) {
#pragma unroll
        for (int r = 0; r < 4; r++) g_pd[t * 16 + quad * 4 + r] = acce[r];
      } else if (col == 1) {
#pragma unroll
        for (int r = 0; r < 4; r++) g_ps[t * 16 + quad * 4 + r] = acce[r];
      }
    }
#pragma unroll
    for (int kk = 0; kk < 4; kk++) a[kk] = na[kk];
  }
}

// ---------------- K3a: column-sum over chunks + block-local scan --------------
__global__ __launch_bounds__(256) void scan_a_kernel()
{
  __shared__ int lds[256];
  const int b = blockIdx.x, t = threadIdx.x;
  const int idx = b * 256 + t;
  int v = 0;
  if (idx < V_NODES) {
#pragma unroll 7
    for (int c = 0; c < NCHUNK; c++) v += (int)g_mat[c * V_NODES + idx];
  }
  lds[t] = v;
  __syncthreads();
  for (int off = 1; off < 256; off <<= 1) {
    int tmp = (t >= off) ? lds[t - off] : 0;
    __syncthreads();
    lds[t] += tmp;
    __syncthreads();
  }
  if (idx < V_NODES) g_row_off[idx] = lds[t] - v;   // local exclusive prefix
  if (t == 255) g_blocksum[b] = lds[255];
}

// ---------------- K3b: fused blocksum-scan + offset-add + m2 base walk --------
__global__ __launch_bounds__(256) void scan_bcm_kernel()
{
  __shared__ int lds[256];
  const int b = blockIdx.x, t = threadIdx.x;       // 196 blocks
  // every block redundantly scans the 196 block sums (trivial)
  const int v = (t < SCAN_BLOCKS) ? g_blocksum[t] : 0;
  lds[t] = v;
  __syncthreads();
  for (int off = 1; off < 256; off <<= 1) {
    int tmp = (t >= off) ? lds[t - off] : 0;
    __syncthreads();
    lds[t] += tmp;
    __syncthreads();
  }
  const int total = lds[255];                      // = E
  const int boff  = (b == 0) ? 0 : lds[b - 1];     // exclusive offset of block b
  const int idx = b * 256 + t;
  if (idx < V_NODES) {
    int running = g_row_off[idx] + boff;           // global exclusive prefix
    g_row_off[idx] = running;
    // m2: matrix counts -> segment bases (in-place)
#pragma unroll 7
    for (int c = 0; c < NCHUNK; c++) {
      const unsigned int cnt = g_mat[c * V_NODES + idx];
      g_mat[c * V_NODES + idx] = (unsigned int)running;
      running += (int)cnt;
    }
  }
  if (b == 0 && t == 0) g_row_off[V_NODES] = total;
}

// ---------------- K4: edge scatter — atomic-free, one 8B write/edge ----------
__global__ void edge_scatter_kernel(
    const int* __restrict__ src, const int* __restrict__ dst, int E)
{
  int e = blockIdx.x * blockDim.x + threadIdx.x;
  if (e >= E) return;
  const int d = dst[e], sn = src[e];
  float logit = g_pd[d] + g_ps[sn] + b2f(g_wsmall[OFF_BEDGE]);
  logit = (logit >= 0.f) ? logit : 0.01f * logit;           // LeakyReLU(0.01)
  const float w = __expf(logit);                            // no max-sub: cancels
  const int c = e >> 14;                                    // chunk
  const int pos = (int)g_mat[c * V_NODES + d] + (int)g_rank16[e];
  g_s_pair[pos] = make_int2(sn, __float_as_int(w));
}

// ---------------- K5: aggregation, 8-deep gather pipeline --------------------
__global__ __launch_bounds__(256) void aggregate_kernel()
{
  const int v = blockIdx.x * 4 + (threadIdx.x >> 6);   // grid 12500 -> v < 50000
  const int lane = threadIdx.x & 63;                   // lane: cols 2l, 2l+1
  const int beg = g_row_off[v], end = g_row_off[v + 1];
  float accx = 0.f, accy = 0.f, ssum = 0.f;
  int i = beg;
  for (; i + 8 <= end; i += 8) {       // 8 gathers in flight
    int2 q[8];
#pragma unroll
    for (int j = 0; j < 8; j++) q[j] = g_s_pair[i + j];
    unsigned int p[8];
#pragma unroll
    for (int j = 0; j < 8; j++)
      p[j] = *reinterpret_cast<const unsigned int*>(g_hv + q[j].x * D_FEAT + lane * 2);
#pragma unroll
    for (int j = 0; j < 8; j++) {
      const float w = __int_as_float(q[j].y);
      ssum += w;
      accx += w * b2f((unsigned short)(p[j] & 0xFFFFu));
      accy += w * b2f((unsigned short)(p[j] >> 16));
    }
  }
  for (; i + 4 <= end; i += 4) {       // 4-deep tail
    int2 q[4];
#pragma unroll
    for (int j = 0; j < 4; j++) q[j] = g_s_pair[i + j];
    unsigned int p[4];
#pragma unroll
    for (int j = 0; j < 4; j++)
      p[j] = *reinterpret_cast<const unsigned int*>(g_hv + q[j].x * D_FEAT + lane * 2);
#pragma unroll
    for (int j = 0; j < 4; j++) {
      const float w = __int_as_float(q[j].y);
      ssum += w;
      accx += w * b2f((unsigned short)(p[j] & 0xFFFFu));
      accy += w * b2f((unsigned short)(p[j] >> 16));
    }
  }
  for (; i < end; i++) {
    const int2 q = g_s_pair[i];
    const float w = __int_as_float(q.y);
    ssum += w;
    const unsigned int pair =
        *reinterpret_cast<const unsigned int*>(g_hv + q.x * D_FEAT + lane * 2);
    accx += w * b2f((unsigned short)(pair & 0xFFFFu));
    accy += w * b2f((unsigned short)(pair >> 16));
  }
  const float inv = (end > beg) ? (1.0f / ssum) : 0.0f;     // empty segment -> c=0
  float c0 = accx * inv, c1 = accy * inv;
  c0 = (c0 > 0.f) ? c0 : (__expf(c0) - 1.f);                // elu
  c1 = (c1 > 0.f) ? c1 : (__expf(c1) - 1.f);
  const unsigned int outp = ((unsigned int)f2b(c1) << 16) | (unsigned int)f2b(c0);
  *reinterpret_cast<unsigned int*>(g_ctx + v * D_FEAT + lane * 2) = outp;
}

// ---------------- K6: GRU weight-stationary + XCD swizzle + LDS DMA pipeline --
__global__ __launch_bounds__(256, 2) void gru_kernel(const float* __restrict__ xf32,
                                                     float* __restrict__ out)
{
  // XCD-grouping swizzle (R23/R25-verified): 2 blocks of a chunk on one XCD.
  const int d = blockIdx.x;
  const int x = d & 7;                       // XCD (round-robin dispatch)
  const int s = d >> 3;                      // slot on that XCD [0, 158)
  const int chunk = x + 8 * (s >> 1);        // 2 slots -> same chunk
  if (chunk >= 625) return;                  // block-uniform guard (14 blocks)
  // double-buffered A-tile staging: [buf][x:0-4K | ctx:4K-8K], linear layout,
  // values pre-permuted at stage so swizzled ds_read is conflict-free.
  __shared__ __attribute__((aligned(16))) char lds_s[2][8192];
  const int half  = s & 1;                   // cg half: 0 -> cg 0..3, 1 -> 4..7
  const int wid   = threadIdx.x >> 6;
  const int lane  = threadIdx.x & 63;
  const int cg    = half * 4 + wid;          // 0..7
  const int col   = lane & 15;
  const int quad  = lane >> 4;
  const int h     = 16 * cg + col;
  const unsigned short* W_ih = g_wsmall + OFF_WIH;
  const unsigned short* W_hh = g_wsmall + OFF_WHH;
  const int isb = g_is_bf16;

  // per-wave constant biases for columns h
  const float br  = b2f(g_wsmall[OFF_BIH + h])       + b2f(g_wsmall[OFF_BHH + h]);
  const float bz  = b2f(g_wsmall[OFF_BIH + 128 + h]) + b2f(g_wsmall[OFF_BHH + 128 + h]);
  const float bn  = b2f(g_wsmall[OFF_BIH + 256 + h]);
  const float bh_ = b2f(g_wsmall[OFF_BHH + 256 + h]);

  // resident B fragments: 24 frags = 96 regs (unified file; launch_bounds(256,2))
  bf16x8 bIHr[4], bHHr[4], bIHz[4], bHHz[4], bIHn[4], bHHn[4];
#pragma unroll
  for (int kk = 0; kk < 4; kk++) {
    const int ko = kk * 32 + quad * 8;
    bIHr[kk] = load_frag(W_ih + h * D_FEAT + ko);
    bHHr[kk] = load_frag(W_hh + h * D_FEAT + ko);
    bIHz[kk] = load_frag(W_ih + (128 + h) * D_FEAT + ko);
    bHHz[kk] = load_frag(W_hh + (128 + h) * D_FEAT + ko);
    bIHn[kk] = load_frag(W_ih + (256 + h) * D_FEAT + ko);
    bHHn[kk] = load_frag(W_hh + (256 + h) * D_FEAT + ko);
  }

  // staging addresses: thread's linear dest offset o in a 4KB tile; the value
  // placed there comes from global offset o ^ ((row&7)<<4) (involution), so a
  // swizzled ds_read returns the logical element (rule #21: both sides).
  const int o_lin = wid * 1024 + lane * 16;                 // dest offset
  const int o_src = o_lin ^ (((o_lin >> 8) & 7) << 4);      // swizzled source
  const char* xbf_b = reinterpret_cast<const char*>(g_xbf);
  const char* ctx_b = reinterpret_cast<const char*>(g_ctx);

  const int t0 = chunk * GCHUNK;
  // prologue: issue DMA for tile t0 into buf 0
  async_copy16(xbf_b + (size_t)t0 * 4096 + o_src, &lds_s[0][wid * 1024]);
  async_copy16(ctx_b + (size_t)t0 * 4096 + o_src, &lds_s[0][4096 + wid * 1024]);

  for (int i = 0; i < GCHUNK; i++) {
    const int t = t0 + i;
    const int buf = i & 1;
    __syncthreads();   // implicit vmcnt(0) drain: buf's DMA complete + visible
    // ds_read frags from staged tile (swizzled, conflict-light)
    bf16x8 ax[4], ac[4];
#pragma unroll
    for (int kk = 0; kk < 4; kk++) {
      const int phys = (col * 256 + kk * 64 + quad * 16) ^ ((col & 7) << 4);
      ax[kk] = *reinterpret_cast<const bf16x8*>(&lds_s[buf][phys]);
      ac[kk] = *reinterpret_cast<const bf16x8*>(&lds_s[buf][4096 + phys]);
    }
    // issue next tile's DMA now (zero-register prefetch; covered by MFMA)
    if (i + 1 < GCHUNK) {
      async_copy16(xbf_b + (size_t)(t + 1) * 4096 + o_src,
                   &lds_s[buf ^ 1][wid * 1024]);
      async_copy16(ctx_b + (size_t)(t + 1) * 4096 + o_src,
                   &lds_s[buf ^ 1][4096 + wid * 1024]);
    }
    // hoisted xv global loads (keep f32 precision path; hidden under MFMAs)
    float xv[4];
    if (isb) {
#pragma unroll
      for (int r = 0; r < 4; r++)
        xv[r] = b2f(g_xbf[(t * 16 + quad * 4 + r) * D_FEAT + h]);
    } else {
#pragma unroll
      for (int r = 0; r < 4; r++)
        xv[r] = xf32[(t * 16 + quad * 4 + r) * D_FEAT + h];
    }
    f32x4 racc, zacc, niacc, nhacc;
    racc[0]=br;  racc[1]=br;  racc[2]=br;  racc[3]=br;
    zacc[0]=bz;  zacc[1]=bz;  zacc[2]=bz;  zacc[3]=bz;
    niacc[0]=bn; niacc[1]=bn; niacc[2]=bn; niacc[3]=bn;
    nhacc[0]=bh_; nhacc[1]=bh_; nhacc[2]=bh_; nhacc[3]=bh_;
#pragma unroll
    for (int kk = 0; kk < 4; kk++) {
      racc  = __builtin_amdgcn_mfma_f32_16x16x32_bf16(ac[kk], bIHr[kk], racc, 0, 0, 0);
      racc  = __builtin_amdgcn_mfma_f32_16x16x32_bf16(ax[kk], bHHr[kk], racc, 0, 0, 0);
      zacc  = __builtin_amdgcn_mfma_f32_16x16x32_bf16(ac[kk], bIHz[kk], zacc, 0, 0, 0);
      zacc  = __builtin_amdgcn_mfma_f32_16x16x32_bf16(ax[kk], bHHz[kk], zacc, 0, 0, 0);
      niacc = __builtin_amdgcn_mfma_f32_16x16x32_bf16(ac[kk], bIHn[kk], niacc, 0, 0, 0);
      nhacc = __builtin_amdgcn_mfma_f32_16x16x32_bf16(ax[kk], bHHn[kk], nhacc, 0, 0, 0);
    }
#pragma unroll
    for (int r = 0; r < 4; r++) {
      const int vrow = t * 16 + quad * 4 + r;
      const float rg = fast_sigmoid(racc[r]);
      const float zg = fast_sigmoid(zacc[r]);
      const float n  = fast_tanh(niacc[r] + rg * nhacc[r]);
      const float hn = (1.f - zg) * n + zg * xv[r];
      out[vrow * D_FEAT + h] = (hn < 0.f) ? 0.f : hn;  // relu; NaN passes (canary)
    }
  }
}

// ---------------- launch ------------------------------------------------------
extern "C" void kernel_launch(void* const* d_in, const int* in_sizes, int n_in,
                              void* d_out, int out_size, void* d_ws, size_t ws_size,
                              hipStream_t stream)
{
  (void)d_ws; (void)ws_size; (void)out_size;

  // resolve inputs by element count (same-size pairs keep dict order)
  int ix = -1, iWe = -1, ibe = -1, iWp = -1, ibp = -1,
      iWih = -1, iWhh = -1, ibih = -1, ibhh = -1, isrc = -1, idst = -1;
  for (int i = 0; i < n_in; i++) {
    const int s = in_sizes[i];
    if      (s == 6400000) ix = i;
    else if (s == 256)     iWe = i;
    else if (s == 1)       ibe = i;
    else if (s == 16384)   iWp = i;
    else if (s == 128)     ibp = i;
    else if (s == 49152)   { if (iWih < 0) iWih = i; else iWhh = i; }
    else if (s == 384)     { if (ibih < 0) ibih = i; else ibhh = i; }
    else if (s == 800000)  { if (isrc < 0) isrc = i; else idst = i; }
  }
  if (ix < 0 || iWe < 0 || ibe < 0 || iWp < 0 || ibp < 0 || iWih < 0 ||
      iWhh < 0 || ibih < 0 || ibhh < 0 || isrc < 0 || idst < 0) {
    ix = 0; iWe = 1; ibe = 2; iWp = 3; ibp = 4;           // dict-order fallback
    iWih = 5; iWhh = 6; ibih = 7; ibhh = 8; isrc = 9; idst = 10;
  }

  const int* src = (const int*)d_in[isrc];
  const int* dst = (const int*)d_in[idst];
  float* out = (float*)d_out;

  probe_kernel<<<1, 256, 0, stream>>>((const unsigned int*)d_in[ix]);
  conv_fused_kernel<<<CONV_X_BLOCKS + CONV_S_BLOCKS, 256, 0, stream>>>(
      d_in[ix],
      d_in[iWe], d_in[iWp], d_in[iWih], d_in[iWhh],
      d_in[ibe], d_in[ibp], d_in[ibih], d_in[ibhh]);
  np_hist_kernel<<<HISTG + WS_BLOCKS, 256, 0, stream>>>(dst);
  scan_a_kernel<<<SCAN_BLOCKS, 256, 0, stream>>>();
  scan_bcm_kernel<<<SCAN_BLOCKS, 256, 0, stream>>>();
  edge_scatter_kernel<<<HIST_BLOCKS, 256, 0, stream>>>(src, dst, E_EDGES);
  aggregate_kernel<<<V_NODES / 4, 256, 0, stream>>>();
  gru_kernel<<<GRU_BLOCKS, 256, 0, stream>>>((const float*)d_in[ix], out);
}

// Round 17
// 207.236 us; speedup vs baseline: 1.1816x; 1.0495x over previous
//
#include <hip/hip_runtime.h>
#include <hip/hip_bf16.h>

// GNN attention layer. V=50000, E=800000, D=H=128. Inputs f32, OUTPUT f32.
//
// R28: R27's 8-deep gather landed (222->217.5); top-5 is now ALL harness
// fills (268 MB re-poison, uncontrollable) -> every kernel of ours < 40.5 us.
// Largest remaining: np_hist (~40, untouched since R19). Its np section has
// the same serial tile-load chain gru had; same precondition holds (4 waves
// of an np block share one chunk -> same 4 KB x-tile). Port R26's verified
// zero-register LDS-DMA pipeline verbatim: 2x4KB dbuf staging via
// global_load_lds, inverse-swizzled global src + swizzled ds_read (rule #21),
// t+1 DMA under t's MFMAs, one barrier/tile. LDS 25->33 KB (ok at lb(256,2)).
// Single variable: np section only. Rest = R27.

#define V_NODES 50000
#define E_EDGES 800000
#define D_FEAT  128
#define GCHUNK  5             // tiles per chunk (625 chunks x 8 cg = 5000 tasks)
#define WS_BLOCKS 1250        // np: 5000 waves / 4 per block
#define GRU_BLOCKS 1264       // gru: 8 xcds x 158 slots (2 blocks/chunk, guard)

#define NCHUNK  49            // ceil(800000/16384) edge chunks
#define CHUNK_E 16384         // edges per chunk (e >> 14)
#define RANGES  4             // node ranges per chunk
#define NODE_R  12500         // nodes per range (25 KB packed LDS histogram)
#define HISTG   (NCHUNK * RANGES)   // 196 hist blocks
#define SCAN_BLOCKS 196       // ceil(50000/256)

typedef short bf16x8 __attribute__((ext_vector_type(8)));  // 8 bf16 in 4 VGPRs
typedef float f32x4  __attribute__((ext_vector_type(4)));
typedef unsigned short u16x4 __attribute__((ext_vector_type(4)));

// small-tensor bf16 pool element offsets
#define OFF_WEDGE 0
#define OFF_WPROJ 256
#define OFF_WIH   16640
#define OFF_WHH   65792
#define OFF_BEDGE 114944
#define OFF_BPROJ 114945
#define OFF_BIH   115073
#define OFF_BHH   115457
#define SMALL_TOTAL 115841
#define CONV_X_BLOCKS   6250   // 1.6M u16x4 / 256
#define CONV_S_BLOCKS   453
#define HIST_BLOCKS     3125   // 800000/256 (edge scatter grid)

// ---- device-global scratch (~58 MB; immune to ws_size) ----
__device__ int   g_is_bf16;
__device__ float g_pd[V_NODES];
__device__ float g_ps[V_NODES];
__device__ __attribute__((aligned(16))) unsigned int g_mat[NCHUNK * V_NODES]; // counts -> bases
__device__ int   g_row_off[V_NODES + 1];
__device__ int   g_blocksum[SCAN_BLOCKS];
__device__ unsigned short g_rank16[E_EDGES];    // within-chunk rank
__device__ __attribute__((aligned(16))) int2 g_s_pair[E_EDGES];  // {src, bits(w)}
__device__ __attribute__((aligned(16))) unsigned short g_xbf[V_NODES * D_FEAT];
__device__ __attribute__((aligned(16))) unsigned short g_wsmall[SMALL_TOTAL + 15];
__device__ __attribute__((aligned(16))) unsigned short g_hv[V_NODES * D_FEAT];
__device__ __attribute__((aligned(16))) unsigned short g_ctx[V_NODES * D_FEAT];

static __device__ __forceinline__ float b2f(unsigned short u) {
  union { unsigned int i; float f; } v; v.i = ((unsigned int)u) << 16; return v.f;
}
static __device__ __forceinline__ unsigned short f2b(float f) {
  unsigned int i = __float_as_uint(f);
  unsigned int r = (i + 0x7FFFu + ((i >> 16) & 1u)) >> 16;  // RNE (NaN stays NaN)
  return (unsigned short)r;
}
static __device__ __forceinline__ bf16x8 load_frag(const unsigned short* p) {
  return *reinterpret_cast<const bf16x8*>(p);  // 16B-aligned vector load
}
static __device__ __forceinline__ float fast_rcp(float x) {
  return __builtin_amdgcn_rcpf(x);             // v_rcp_f32, ~1 ulp
}
static __device__ __forceinline__ float fast_sigmoid(float x) {
  return fast_rcp(1.f + __expf(-x));           // x<<0: exp->inf, rcp->0. ok
}
static __device__ __forceinline__ float fast_tanh(float y) {
  // 1 - 2/(e^{2y}+1); y>>0: exp->inf, rcp->0 -> 1; y<<0: exp->0 -> -1; NaN->NaN
  return 1.f - 2.f * fast_rcp(__expf(2.f * y) + 1.f);
}
// async global->LDS DMA, 16B per lane; lds ptr is wave-uniform base
static __device__ __forceinline__ void async_copy16(const void* g, void* l) {
  __builtin_amdgcn_global_load_lds(
      (const __attribute__((address_space(1))) void*)g,
      (__attribute__((address_space(3))) void*)l, 16, 0, 0);
}

// ---------------- P: dtype probe on x ----------------------------------------
__global__ void probe_kernel(const unsigned int* __restrict__ x)
{
  __shared__ int cnt;
  if (threadIdx.x == 0) cnt = 0;
  __syncthreads();
  const unsigned int w  = x[threadIdx.x];
  const unsigned int lo = w & 0xFFFFu;
  const unsigned int ex = (lo >> 7) & 0xFFu;
  if (lo != 0u && ex >= 118u && ex <= 132u) atomicAdd(&cnt, 1);
  __syncthreads();
  if (threadIdx.x == 0) g_is_bf16 = (cnt >= 200) ? 1 : 0;
}

// ---------------- C: fused convert-x | convert-smalls ------------------------
__global__ void conv_fused_kernel(
    const void* __restrict__ x,
    const void* p0, const void* p1, const void* p2, const void* p3,
    const void* p4, const void* p5, const void* p6, const void* p7)
{
  const int b = blockIdx.x;
  if (b < CONV_X_BLOCKS) {
    const int t = b * 256 + threadIdx.x;
    if (g_is_bf16) {
      reinterpret_cast<u16x4*>(g_xbf)[t] = reinterpret_cast<const u16x4*>(x)[t];
    } else {
      const float4 v = reinterpret_cast<const float4*>(x)[t];
      u16x4 o; o.x = f2b(v.x); o.y = f2b(v.y); o.z = f2b(v.z); o.w = f2b(v.w);
      reinterpret_cast<u16x4*>(g_xbf)[t] = o;
    }
  } else {
    const int i = (b - CONV_X_BLOCKS) * 256 + threadIdx.x;
    if (i >= SMALL_TOTAL) return;
    const int offs[9] = {OFF_WEDGE, OFF_WPROJ, OFF_WIH, OFF_WHH,
                         OFF_BEDGE, OFF_BPROJ, OFF_BIH, OFF_BHH, SMALL_TOTAL};
    const void* ps[8] = {p0, p1, p2, p3, p4, p5, p6, p7};
    int r = 0;
#pragma unroll
    for (int k = 0; k < 8; k++) if (i >= offs[k]) r = k;
    const int j = i - offs[r];
    g_wsmall[i] = g_is_bf16
        ? reinterpret_cast<const unsigned short*>(ps[r])[j]
        : f2b(reinterpret_cast<const float*>(ps[r])[j]);
  }
}

// ---------------- K1: hist(c,r) int4-ILP LDS + node_pre (LDS-DMA tiles) ------
__global__ __launch_bounds__(256, 2) void np_hist_kernel(const int* __restrict__ dst)
{
  __shared__ unsigned int hloc[NODE_R / 2];  // 25 KB; 2 node counters per word
  __shared__ __attribute__((aligned(16))) char lds_x[2][4096];  // np x-tile dbuf
  const int b = blockIdx.x;
  if (b < HISTG) {                           // ---- chunk x range histogram ----
    const int c  = b >> 2;                   // chunk [0,49)
    const int r0 = (b & 3) * NODE_R;         // range base node
    for (int i = threadIdx.x; i < NODE_R / 2; i += 256) hloc[i] = 0u;
    __syncthreads();
    const int ebase = c * CHUNK_E;
    const int ecnt  = min(CHUNK_E, E_EDGES - ebase);   // always multiple of 4
    const int4* dst4 = reinterpret_cast<const int4*>(dst + ebase);
    const int n4 = ecnt >> 2;
    for (int i = threadIdx.x; i < n4; i += 256) {
      const int4 d4 = dst4[i];               // 4 edges per thread per iter
      const int e0 = ebase + (i << 2);
      const unsigned int rx = (unsigned int)(d4.x - r0);
      const unsigned int ry = (unsigned int)(d4.y - r0);
      const unsigned int rz = (unsigned int)(d4.z - r0);
      const unsigned int rw = (unsigned int)(d4.w - r0);
      if (rx < (unsigned int)NODE_R) {       // 4 independent atomics pipeline
        const unsigned int sh = (rx & 1u) << 4;
        const unsigned int old = atomicAdd(&hloc[rx >> 1], 1u << sh);
        g_rank16[e0] = (unsigned short)((old >> sh) & 0xFFFFu);
      }
      if (ry < (unsigned int)NODE_R) {
        const unsigned int sh = (ry & 1u) << 4;
        const unsigned int old = atomicAdd(&hloc[ry >> 1], 1u << sh);
        g_rank16[e0 + 1] = (unsigned short)((old >> sh) & 0xFFFFu);
      }
      if (rz < (unsigned int)NODE_R) {
        const unsigned int sh = (rz & 1u) << 4;
        const unsigned int old = atomicAdd(&hloc[rz >> 1], 1u << sh);
        g_rank16[e0 + 2] = (unsigned short)((old >> sh) & 0xFFFFu);
      }
      if (rw < (unsigned int)NODE_R) {
        const unsigned int sh = (rw & 1u) << 4;
        const unsigned int old = atomicAdd(&hloc[rw >> 1], 1u << sh);
        g_rank16[e0 + 3] = (unsigned short)((old >> sh) & 0xFFFFu);
      }
    }
    __syncthreads();
    // vectorized writeout: one hloc word -> uint2 {lo count, hi count}
    uint2* mout = reinterpret_cast<uint2*>(&g_mat[c * V_NODES + r0]);
    for (int i = threadIdx.x; i < NODE_R / 2; i += 256) {
      const unsigned int w = hloc[i];
      mout[i] = make_uint2(w & 0xFFFFu, w >> 16);
    }
    return;
  }
  // ---- node_pre: 4 waves share one chunk (g=4m+wid -> chunk block-uniform) --
  const int wid   = threadIdx.x >> 6;
  const int g     = (b - HISTG) * 4 + wid;
  const int lane  = threadIdx.x & 63;
  const int cg    = g & 7;
  const int chunk = g >> 3;                  // [0, 625), block-uniform
  const int col   = lane & 15;
  const int quad  = lane >> 4;
  const int h     = 16 * cg + col;

  // resident B fragments: W_proj rows [16cg, 16cg+16)
  bf16x8 bw[4];
#pragma unroll
  for (int kk = 0; kk < 4; kk++)
    bw[kk] = load_frag(g_wsmall + OFF_WPROJ + h * D_FEAT + kk * 32 + quad * 8);
  // cg 0 also owns the edge projections (cols 0/1 of W_edge)
  bf16x8 be[4];
#pragma unroll
  for (int kk = 0; kk < 4; kk++) { be[kk] = bf16x8{0,0,0,0,0,0,0,0}; }
  if (cg == 0 && col < 2) {
#pragma unroll
    for (int kk = 0; kk < 4; kk++)
      be[kk] = load_frag(g_wsmall + OFF_WEDGE + col * D_FEAT + kk * 32 + quad * 8);
  }
  const float bp = b2f(g_wsmall[OFF_BPROJ + h]);

  // staging addresses (R26-verified involution): linear LDS dest, swizzled
  // global source, swizzled ds_read returns the logical element.
  const int o_lin = wid * 1024 + lane * 16;
  const int o_src = o_lin ^ (((o_lin >> 8) & 7) << 4);
  const char* xbf_b = reinterpret_cast<const char*>(g_xbf);

  const int t0 = chunk * GCHUNK;
  async_copy16(xbf_b + (size_t)t0 * 4096 + o_src, &lds_x[0][wid * 1024]);

  for (int i = 0; i < GCHUNK; i++) {
    const int t = t0 + i;
    const int buf = i & 1;
    __syncthreads();   // implicit vmcnt(0): buf's DMA complete + visible
    bf16x8 a[4];
#pragma unroll
    for (int kk = 0; kk < 4; kk++) {
      const int phys = (col * 256 + kk * 64 + quad * 16) ^ ((col & 7) << 4);
      a[kk] = *reinterpret_cast<const bf16x8*>(&lds_x[buf][phys]);
    }
    if (i + 1 < GCHUNK)
      async_copy16(xbf_b + (size_t)(t + 1) * 4096 + o_src,
                   &lds_x[buf ^ 1][wid * 1024]);
    f32x4 acc; acc[0]=0.f; acc[1]=0.f; acc[2]=0.f; acc[3]=0.f;
#pragma unroll
    for (int kk = 0; kk < 4; kk++)
      acc = __builtin_amdgcn_mfma_f32_16x16x32_bf16(a[kk], bw[kk], acc, 0, 0, 0);
#pragma unroll
    for (int r = 0; r < 4; r++)
      g_hv[(t * 16 + quad * 4 + r) * D_FEAT + h] = f2b(acc[r] + bp);
    if (cg == 0) {
      f32x4 acce; acce[0]=0.f; acce[1]=0.f; acce[2]=0.f; acce[3]=0.f;
#pragma unroll
      for (int kk = 0; kk < 4; kk++)
        acce = __builtin_amdgcn_mfma_f32_16x16x32_bf16(a[kk], be[kk], acce, 0, 0, 0);
      if (col == 0) {
#pragma unroll
        for (int r = 0; r < 4; r++) g_pd[t * 16 + quad * 4 + r] = acce[r];
      } else if (col == 1) {
#pragma unroll
        for (int r = 0; r < 4; r++) g_ps[t * 16 + quad * 4 + r] = acce[r];
      }
    }
  }
}

// ---------------- K3a: column-sum over chunks + block-local scan --------------
__global__ __launch_bounds__(256) void scan_a_kernel()
{
  __shared__ int lds[256];
  const int b = blockIdx.x, t = threadIdx.x;
  const int idx = b * 256 + t;
  int v = 0;
  if (idx < V_NODES) {
#pragma unroll 7
    for (int c = 0; c < NCHUNK; c++) v += (int)g_mat[c * V_NODES + idx];
  }
  lds[t] = v;
  __syncthreads();
  for (int off = 1; off < 256; off <<= 1) {
    int tmp = (t >= off) ? lds[t - off] : 0;
    __syncthreads();
    lds[t] += tmp;
    __syncthreads();
  }
  if (idx < V_NODES) g_row_off[idx] = lds[t] - v;   // local exclusive prefix
  if (t == 255) g_blocksum[b] = lds[255];
}

// ---------------- K3b: fused blocksum-scan + offset-add + m2 base walk --------
__global__ __launch_bounds__(256) void scan_bcm_kernel()
{
  __shared__ int lds[256];
  const int b = blockIdx.x, t = threadIdx.x;       // 196 blocks
  // every block redundantly scans the 196 block sums (trivial)
  const int v = (t < SCAN_BLOCKS) ? g_blocksum[t] : 0;
  lds[t] = v;
  __syncthreads();
  for (int off = 1; off < 256; off <<= 1) {
    int tmp = (t >= off) ? lds[t - off] : 0;
    __syncthreads();
    lds[t] += tmp;
    __syncthreads();
  }
  const int total = lds[255];                      // = E
  const int boff  = (b == 0) ? 0 : lds[b - 1];     // exclusive offset of block b
  const int idx = b * 256 + t;
  if (idx < V_NODES) {
    int running = g_row_off[idx] + boff;           // global exclusive prefix
    g_row_off[idx] = running;
    // m2: matrix counts -> segment bases (in-place)
#pragma unroll 7
    for (int c = 0; c < NCHUNK; c++) {
      const unsigned int cnt = g_mat[c * V_NODES + idx];
      g_mat[c * V_NODES + idx] = (unsigned int)running;
      running += (int)cnt;
    }
  }
  if (b == 0 && t == 0) g_row_off[V_NODES] = total;
}

// ---------------- K4: edge scatter — atomic-free, one 8B write/edge ----------
__global__ void edge_scatter_kernel(
    const int* __restrict__ src, const int* __restrict__ dst, int E)
{
  int e = blockIdx.x * blockDim.x + threadIdx.x;
  if (e >= E) return;
  const int d = dst[e], sn = src[e];
  float logit = g_pd[d] + g_ps[sn] + b2f(g_wsmall[OFF_BEDGE]);
  logit = (logit >= 0.f) ? logit : 0.01f * logit;           // LeakyReLU(0.01)
  const float w = __expf(logit);                            // no max-sub: cancels
  const int c = e >> 14;                                    // chunk
  const int pos = (int)g_mat[c * V_NODES + d] + (int)g_rank16[e];
  g_s_pair[pos] = make_int2(sn, __float_as_int(w));
}

// ---------------- K5: aggregation, 8-deep gather pipeline --------------------
__global__ __launch_bounds__(256) void aggregate_kernel()
{
  const int v = blockIdx.x * 4 + (threadIdx.x >> 6);   // grid 12500 -> v < 50000
  const int lane = threadIdx.x & 63;                   // lane: cols 2l, 2l+1
  const int beg = g_row_off[v], end = g_row_off[v + 1];
  float accx = 0.f, accy = 0.f, ssum = 0.f;
  int i = beg;
  for (; i + 8 <= end; i += 8) {       // 8 gathers in flight
    int2 q[8];
#pragma unroll
    for (int j = 0; j < 8; j++) q[j] = g_s_pair[i + j];
    unsigned int p[8];
#pragma unroll
    for (int j = 0; j < 8; j++)
      p[j] = *reinterpret_cast<const unsigned int*>(g_hv + q[j].x * D_FEAT + lane * 2);
#pragma unroll
    for (int j = 0; j < 8; j++) {
      const float w = __int_as_float(q[j].y);
      ssum += w;
      accx += w * b2f((unsigned short)(p[j] & 0xFFFFu));
      accy += w * b2f((unsigned short)(p[j] >> 16));
    }
  }
  for (; i + 4 <= end; i += 4) {       // 4-deep tail
    int2 q[4];
#pragma unroll
    for (int j = 0; j < 4; j++) q[j] = g_s_pair[i + j];
    unsigned int p[4];
#pragma unroll
    for (int j = 0; j < 4; j++)
      p[j] = *reinterpret_cast<const unsigned int*>(g_hv + q[j].x * D_FEAT + lane * 2);
#pragma unroll
    for (int j = 0; j < 4; j++) {
      const float w = __int_as_float(q[j].y);
      ssum += w;
      accx += w * b2f((unsigned short)(p[j] & 0xFFFFu));
      accy += w * b2f((unsigned short)(p[j] >> 16));
    }
  }
  for (; i < end; i++) {
    const int2 q = g_s_pair[i];
    const float w = __int_as_float(q.y);
    ssum += w;
    const unsigned int pair =
        *reinterpret_cast<const unsigned int*>(g_hv + q.x * D_FEAT + lane * 2);
    accx += w * b2f((unsigned short)(pair & 0xFFFFu));
    accy += w * b2f((unsigned short)(pair >> 16));
  }
  const float inv = (end > beg) ? (1.0f / ssum) : 0.0f;     // empty segment -> c=0
  float c0 = accx * inv, c1 = accy * inv;
  c0 = (c0 > 0.f) ? c0 : (__expf(c0) - 1.f);                // elu
  c1 = (c1 > 0.f) ? c1 : (__expf(c1) - 1.f);
  const unsigned int outp = ((unsigned int)f2b(c1) << 16) | (unsigned int)f2b(c0);
  *reinterpret_cast<unsigned int*>(g_ctx + v * D_FEAT + lane * 2) = outp;
}

// ---------------- K6: GRU weight-stationary + XCD swizzle + LDS DMA pipeline --
__global__ __launch_bounds__(256, 2) void gru_kernel(const float* __restrict__ xf32,
                                                     float* __restrict__ out)
{
  // XCD-grouping swizzle (R23/R25-verified): 2 blocks of a chunk on one XCD.
  const int d = blockIdx.x;
  const int x = d & 7;                       // XCD (round-robin dispatch)
  const int s = d >> 3;                      // slot on that XCD [0, 158)
  const int chunk = x + 8 * (s >> 1);        // 2 slots -> same chunk
  if (chunk >= 625) return;                  // block-uniform guard (14 blocks)
  // double-buffered A-tile staging: [buf][x:0-4K | ctx:4K-8K], linear layout,
  // values pre-permuted at stage so swizzled ds_read is conflict-free.
  __shared__ __attribute__((aligned(16))) char lds_s[2][8192];
  const int half  = s & 1;                   // cg half: 0 -> cg 0..3, 1 -> 4..7
  const int wid   = threadIdx.x >> 6;
  const int lane  = threadIdx.x & 63;
  const int cg    = half * 4 + wid;          // 0..7
  const int col   = lane & 15;
  const int quad  = lane >> 4;
  const int h     = 16 * cg + col;
  const unsigned short* W_ih = g_wsmall + OFF_WIH;
  const unsigned short* W_hh = g_wsmall + OFF_WHH;
  const int isb = g_is_bf16;

  // per-wave constant biases for columns h
  const float br  = b2f(g_wsmall[OFF_BIH + h])       + b2f(g_wsmall[OFF_BHH + h]);
  const float bz  = b2f(g_wsmall[OFF_BIH + 128 + h]) + b2f(g_wsmall[OFF_BHH + 128 + h]);
  const float bn  = b2f(g_wsmall[OFF_BIH + 256 + h]);
  const float bh_ = b2f(g_wsmall[OFF_BHH + 256 + h]);

  // resident B fragments: 24 frags = 96 regs (unified file; launch_bounds(256,2))
  bf16x8 bIHr[4], bHHr[4], bIHz[4], bHHz[4], bIHn[4], bHHn[4];
#pragma unroll
  for (int kk = 0; kk < 4; kk++) {
    const int ko = kk * 32 + quad * 8;
    bIHr[kk] = load_frag(W_ih + h * D_FEAT + ko);
    bHHr[kk] = load_frag(W_hh + h * D_FEAT + ko);
    bIHz[kk] = load_frag(W_ih + (128 + h) * D_FEAT + ko);
    bHHz[kk] = load_frag(W_hh + (128 + h) * D_FEAT + ko);
    bIHn[kk] = load_frag(W_ih + (256 + h) * D_FEAT + ko);
    bHHn[kk] = load_frag(W_hh + (256 + h) * D_FEAT + ko);
  }

  // staging addresses: thread's linear dest offset o in a 4KB tile; the value
  // placed there comes from global offset o ^ ((row&7)<<4) (involution), so a
  // swizzled ds_read returns the logical element (rule #21: both sides).
  const int o_lin = wid * 1024 + lane * 16;                 // dest offset
  const int o_src = o_lin ^ (((o_lin >> 8) & 7) << 4);      // swizzled source
  const char* xbf_b = reinterpret_cast<const char*>(g_xbf);
  const char* ctx_b = reinterpret_cast<const char*>(g_ctx);

  const int t0 = chunk * GCHUNK;
  // prologue: issue DMA for tile t0 into buf 0
  async_copy16(xbf_b + (size_t)t0 * 4096 + o_src, &lds_s[0][wid * 1024]);
  async_copy16(ctx_b + (size_t)t0 * 4096 + o_src, &lds_s[0][4096 + wid * 1024]);

  for (int i = 0; i < GCHUNK; i++) {
    const int t = t0 + i;
    const int buf = i & 1;
    __syncthreads();   // implicit vmcnt(0) drain: buf's DMA complete + visible
    // ds_read frags from staged tile (swizzled, conflict-light)
    bf16x8 ax[4], ac[4];
#pragma unroll
    for (int kk = 0; kk < 4; kk++) {
      const int phys = (col * 256 + kk * 64 + quad * 16) ^ ((col & 7) << 4);
      ax[kk] = *reinterpret_cast<const bf16x8*>(&lds_s[buf][phys]);
      ac[kk] = *reinterpret_cast<const bf16x8*>(&lds_s[buf][4096 + phys]);
    }
    // issue next tile's DMA now (zero-register prefetch; covered by MFMA)
    if (i + 1 < GCHUNK) {
      async_copy16(xbf_b + (size_t)(t + 1) * 4096 + o_src,
                   &lds_s[buf ^ 1][wid * 1024]);
      async_copy16(ctx_b + (size_t)(t + 1) * 4096 + o_src,
                   &lds_s[buf ^ 1][4096 + wid * 1024]);
    }
    // hoisted xv global loads (keep f32 precision path; hidden under MFMAs)
    float xv[4];
    if (isb) {
#pragma unroll
      for (int r = 0; r < 4; r++)
        xv[r] = b2f(g_xbf[(t * 16 + quad * 4 + r) * D_FEAT + h]);
    } else {
#pragma unroll
      for (int r = 0; r < 4; r++)
        xv[r] = xf32[(t * 16 + quad * 4 + r) * D_FEAT + h];
    }
    f32x4 racc, zacc, niacc, nhacc;
    racc[0]=br;  racc[1]=br;  racc[2]=br;  racc[3]=br;
    zacc[0]=bz;  zacc[1]=bz;  zacc[2]=bz;  zacc[3]=bz;
    niacc[0]=bn; niacc[1]=bn; niacc[2]=bn; niacc[3]=bn;
    nhacc[0]=bh_; nhacc[1]=bh_; nhacc[2]=bh_; nhacc[3]=bh_;
#pragma unroll
    for (int kk = 0; kk < 4; kk++) {
      racc  = __builtin_amdgcn_mfma_f32_16x16x32_bf16(ac[kk], bIHr[kk], racc, 0, 0, 0);
      racc  = __builtin_amdgcn_mfma_f32_16x16x32_bf16(ax[kk], bHHr[kk], racc, 0, 0, 0);
      zacc  = __builtin_amdgcn_mfma_f32_16x16x32_bf16(ac[kk], bIHz[kk], zacc, 0, 0, 0);
      zacc  = __builtin_amdgcn_mfma_f32_16x16x32_bf16(ax[kk], bHHz[kk], zacc, 0, 0, 0);
      niacc = __builtin_amdgcn_mfma_f32_16x16x32_bf16(ac[kk], bIHn[kk], niacc, 0, 0, 0);
      nhacc = __builtin_amdgcn_mfma_f32_16x16x32_bf16(ax[kk], bHHn[kk], nhacc, 0, 0, 0);
    }
#pragma unroll
    for (int r = 0; r < 4; r++) {
      const int vrow = t * 16 + quad * 4 + r;
      const float rg = fast_sigmoid(racc[r]);
      const float zg = fast_sigmoid(zacc[r]);
      const float n  = fast_tanh(niacc[r] + rg * nhacc[r]);
      const float hn = (1.f - zg) * n + zg * xv[r];
      out[vrow * D_FEAT + h] = (hn < 0.f) ? 0.f : hn;  // relu; NaN passes (canary)
    }
  }
}

// ---------------- launch ------------------------------------------------------
extern "C" void kernel_launch(void* const* d_in, const int* in_sizes, int n_in,
                              void* d_out, int out_size, void* d_ws, size_t ws_size,
                              hipStream_t stream)
{
  (void)d_ws; (void)ws_size; (void)out_size;

  // resolve inputs by element count (same-size pairs keep dict order)
  int ix = -1, iWe = -1, ibe = -1, iWp = -1, ibp = -1,
      iWih = -1, iWhh = -1, ibih = -1, ibhh = -1, isrc = -1, idst = -1;
  for (int i = 0; i < n_in; i++) {
    const int s = in_sizes[i];
    if      (s == 6400000) ix = i;
    else if (s == 256)     iWe = i;
    else if (s == 1)       ibe = i;
    else if (s == 16384)   iWp = i;
    else if (s == 128)     ibp = i;
    else if (s == 49152)   { if (iWih < 0) iWih = i; else iWhh = i; }
    else if (s == 384)     { if (ibih < 0) ibih = i; else ibhh = i; }
    else if (s == 800000)  { if (isrc < 0) isrc = i; else idst = i; }
  }
  if (ix < 0 || iWe < 0 || ibe < 0 || iWp < 0 || ibp < 0 || iWih < 0 ||
      iWhh < 0 || ibih < 0 || ibhh < 0 || isrc < 0 || idst < 0) {
    ix = 0; iWe = 1; ibe = 2; iWp = 3; ibp = 4;           // dict-order fallback
    iWih = 5; iWhh = 6; ibih = 7; ibhh = 8; isrc = 9; idst = 10;
  }

  const int* src = (const int*)d_in[isrc];
  const int* dst = (const int*)d_in[idst];
  float* out = (float*)d_out;

  probe_kernel<<<1, 256, 0, stream>>>((const unsigned int*)d_in[ix]);
  conv_fused_kernel<<<CONV_X_BLOCKS + CONV_S_BLOCKS, 256, 0, stream>>>(
      d_in[ix],
      d_in[iWe], d_in[iWp], d_in[iWih], d_in[iWhh],
      d_in[ibe], d_in[ibp], d_in[ibih], d_in[ibhh]);
  np_hist_kernel<<<HISTG + WS_BLOCKS, 256, 0, stream>>>(dst);
  scan_a_kernel<<<SCAN_BLOCKS, 256, 0, stream>>>();
  scan_bcm_kernel<<<SCAN_BLOCKS, 256, 0, stream>>>();
  edge_scatter_kernel<<<HIST_BLOCKS, 256, 0, stream>>>(src, dst, E_EDGES);
  aggregate_kernel<<<V_NODES / 4, 256, 0, stream>>>();
  gru_kernel<<<GRU_BLOCKS, 256, 0, stream>>>((const float*)d_in[ix], out);
}